// Round 4
// baseline (3601.468 us; speedup 1.0000x reference)
//
#include <hip/hip_runtime.h>
#include <hip/hip_bf16.h>
#include <math.h>

// Problem constants
constexpr int NSAMP  = 131072;
constexpr int NEV    = 128;
constexpr int ASIZE  = 512;
constexpr int LDIM   = 16;
constexpr int NLAYER = 7;
constexpr int NFFT   = 393216;     // padded FFT length (3*NSAMP)
constexpr int MHALF  = 196608;     // NFFT/2
constexpr int QN     = 65536;      // MHALF/3 (radix-2 FFT length)
constexpr double TWO_PI = 6.283185307179586;

// Strategy: the reference output is dominated (max ~1.879e-4) by GHOST ECHOES
// caused by float32 quantization of the phase ramp theta_k = f32-chain of
// (2k*pi_f32/196609f)*s_f32 (theta up to 4.1e5 rad, ulp ~0.03). We therefore
// compute the REAL pipeline: f32-faithful front-end (bit-exact bt -> s),
// f32-quantized phases, fp64 transforms (internal FFT roundoff is benign).
// Linearity: sum per-event spectra, ONE inverse real FFT.

// ---------------------------------------------------------------------------
// K1: latent tree, strict f32 (sequential dot order, mul+add, no fma).
// ---------------------------------------------------------------------------
__global__ __launch_bounds__(256) void tree_f32(
    const float* __restrict__ base, const float* __restrict__ to_off_w,
    const float* __restrict__ split_w, const float* __restrict__ split_b,
    float* __restrict__ xF, float* __restrict__ sF)
{
    __shared__ float xA[NEV*LDIM], xB[NEV*LDIM], bA[NEV], bB[NEV];
    const int tid = threadIdx.x;
    if (tid < LDIM) xA[tid] = base[tid];
    if (tid == 0) bA[0] = 0.0f;
    __syncthreads();
    float* xi = xA; float* xo = xB; float* bi = bA; float* bo = bB;
    for (int i = 0; i < NLAYER; ++i) {
        const int ein = 1 << i;
        const float scale = 1.0f / (float)(1 << i);      // exact pow2
        for (int idx = tid; idx < ein*32; idx += 256) {
            const int ep = idx >> 5, o2 = idx & 31;
            const float* wr = split_w + (i*32 + o2)*LDIM;
            const float* xr = xi + ep*LDIM;
            float s = __fmul_rn(xr[0], wr[0]);
            for (int l = 1; l < LDIM; ++l)
                s = __fadd_rn(s, __fmul_rn(xr[l], wr[l]));
            s = __fadd_rn(s, split_b[i*32 + o2]);        // bias AFTER dot
            xo[(ep*2 + (o2>>4))*LDIM + (o2&15)] = s;
        }
        for (int idx = tid; idx < ein*2; idx += 256) {
            const int ep = idx >> 1, o = idx & 1;
            const float* wr = to_off_w + (i*2 + o)*LDIM;
            const float* xr = xi + ep*LDIM;
            float v = __fmul_rn(xr[0], wr[0]);
            for (int l = 1; l < LDIM; ++l)
                v = __fadd_rn(v, __fmul_rn(xr[l], wr[l]));
            // sigmoid = 1/(1+exp(-v)); f64 exp rounded = correctly-rounded expf
            const float ef = (float)exp(-(double)v);
            const float sg = __fdiv_rn(1.0f, __fadd_rn(1.0f, ef));
            bo[ep*2 + o] = __fadd_rn(bi[ep], __fmul_rn(sg, scale));
        }
        __syncthreads();
        float* t;
        t = xi; xi = xo; xo = t;
        t = bi; bi = bo; bo = t;
    }
    for (int idx = tid; idx < NEV*LDIM; idx += 256) xF[idx] = xi[idx];
    for (int e = tid; e < NEV; e += 256)             // shift*n*0.5 (both exact)
        sF[e] = __fmul_rn(__fmul_rn(bi[e], 131072.0f), 0.5f);
}

// ---------------------------------------------------------------------------
// K2: per-event signal, strict f32 chain (mix -> window -> norm -> amp).
// ---------------------------------------------------------------------------
__global__ __launch_bounds__(256) void events_f32(
    const float* __restrict__ atoms, const float* __restrict__ to_atoms_w,
    const float* __restrict__ to_atoms_b, const float* __restrict__ to_amp_w,
    const float* __restrict__ to_amp_b, const float* __restrict__ xF,
    float* __restrict__ zf)
{
    const int e = blockIdx.x;
    const int tid = threadIdx.x;
    __shared__ float mixS[32];
    __shared__ float evS[ASIZE];
    __shared__ double red[256];
    __shared__ float scl[2];
    const float* x = xF + e*LDIM;
    if (tid < 32) {
        const float* wr = to_atoms_w + tid*LDIM;
        float m = __fmul_rn(x[0], wr[0]);
        for (int l = 1; l < LDIM; ++l) m = __fadd_rn(m, __fmul_rn(x[l], wr[l]));
        mixS[tid] = __fadd_rn(m, to_atoms_b[tid]);
    }
    __syncthreads();
    double ss = 0.0;
    for (int u = tid; u < ASIZE; u += 256) {
        float v = __fmul_rn(mixS[0], atoms[u]);
        for (int a = 1; a < 32; ++a)
            v = __fadd_rn(v, __fmul_rn(mixS[a], atoms[a*ASIZE + u]));
        // window = 0.54 - 0.46*cos((2*pi)*u/512), f32 chain
        const float ang = __fdiv_rn(__fmul_rn(6.283185307179586f, (float)u), 512.0f);
        const float cw = (float)cos((double)ang);    // correctly-rounded cosf
        const float w  = __fsub_rn(0.54f, __fmul_rn(0.46f, cw));
        v = __fmul_rn(v, w);
        evS[u] = v;
        ss += (double)v * (double)v;                 // norm slop is benign
    }
    red[tid] = ss; __syncthreads();
    for (int s = 128; s > 0; s >>= 1) { if (tid < s) red[tid] += red[tid+s]; __syncthreads(); }
    if (tid == 0) {
        const float nf = (float)sqrt(red[0]);
        scl[0] = __fadd_rn(nf, 1e-8f);
        float a = __fmul_rn(x[0], to_amp_w[0]);
        for (int l = 1; l < LDIM; ++l) a = __fadd_rn(a, __fmul_rn(x[l], to_amp_w[l]));
        scl[1] = __fadd_rn(a, to_amp_b[0]);
    }
    __syncthreads();
    const float den = scl[0], amp = scl[1];
    for (int u = tid; u < ASIZE; u += 256)
        zf[e*ASIZE + u] = __fmul_rn(__fdiv_rn(evS[u], den), amp);
}

// ---------------------------------------------------------------------------
// K3 (hot): direct forward DFT of the 512-sample signals at all 196609 bins,
// f32-quantized phase applied per event, summed over events (fp64).
// H_k = sum_e [sum_u z_e[u] e^{-2pi i k u / N}] * e^{i theta_hat(e,k)}
// theta_hat = f32( f32( f32(2k * pi_f32) / 196609f ) * s_e )   <-- THE ghosts
// ---------------------------------------------------------------------------
__global__ __launch_bounds__(256) void forward_spec(
    const float* __restrict__ zf, const float* __restrict__ sF,
    double2* __restrict__ H)
{
    __shared__ double2 zsh[256];
    __shared__ float sSh[NEV];
    const int tid = threadIdx.x;
    const int k = blockIdx.x*256 + tid;
    if (tid < NEV) sSh[tid] = sF[tid];
    const float c2 = __fdiv_rn(__fmul_rn((float)(2*k), 3.14159274101257324f),
                               196609.0f);
    double sa, ca;
    sincos(TWO_PI * (double)k / (double)NFFT, &sa, &ca);   // rotation step
    double accR = 0.0, accI = 0.0;
    for (int e = 0; e < NEV; ++e) {
        __syncthreads();
        if (tid < 128) {
            const float4 z4 = ((const float4*)(zf + e*ASIZE))[tid];
            zsh[2*tid]   = make_double2((double)z4.x, (double)z4.y);
            zsh[2*tid+1] = make_double2((double)z4.z, (double)z4.w);
        }
        __syncthreads();
        // S = sum_u z[u] * e^{-i a u},  (cr,ci) = e^{-i a u} via recurrence
        double cr = 1.0, ci = 0.0, sr = 0.0, si = 0.0;
        #pragma unroll 8
        for (int u2 = 0; u2 < 256; ++u2) {
            const double2 z = zsh[u2];
            sr = fma(z.x, cr, sr); si = fma(z.x, ci, si);
            double t1 = fma(cr, ca, ci*sa);
            double t2 = fma(ci, ca, -(cr*sa));
            cr = t1; ci = t2;
            sr = fma(z.y, cr, sr); si = fma(z.y, ci, si);
            t1 = fma(cr, ca, ci*sa);
            t2 = fma(ci, ca, -(cr*sa));
            cr = t1; ci = t2;
        }
        const float th = __fmul_rn(c2, sSh[e]);   // f32-quantized phase
        double ps, pc; sincos((double)th, &ps, &pc);  // exact reduction of f32 value
        accR += sr*pc - si*ps;
        accI += sr*ps + si*pc;
    }
    if (k <= MHALF) H[k] = make_double2(accR, accI);
}

// ---------------------------------------------------------------------------
// K4: pack Hermitian spectrum (with irfft's Im-drop at DC/Nyquist) into the
// half-size complex sequence G, deinterleaved mod 3 for the radix-3 split.
// G_k = 0.5*[(H_k + conj(H_{M-k})) + i*e^{+2pi i k/N}*(H_k - conj(H_{M-k}))]
// ---------------------------------------------------------------------------
__global__ __launch_bounds__(256) void pack_g(
    const double2* __restrict__ H, double2* __restrict__ Ga)
{
    const int k = blockIdx.x*256 + threadIdx.x;   // < 196608
    double2 Hk = H[k], Hm = H[MHALF - k];
    if (k == 0) { Hk.y = 0.0; Hm.y = 0.0; }       // irfft drops these imags
    const double Pr = Hk.x + Hm.x, Pi_ = Hk.y - Hm.y;
    const double Qr = Hk.x - Hm.x, Qi = Hk.y + Hm.y;
    double sw, cw; sincos(TWO_PI * (double)k / (double)NFFT, &sw, &cw);
    const double WQr = cw*Qr - sw*Qi;
    const double WQi = cw*Qi + sw*Qr;
    double2 G;
    G.x = 0.5*(Pr - WQi);
    G.y = 0.5*(Pi_ + WQr);
    Ga[(k % 3)*QN + (k/3)] = G;
}

// ---------------------------------------------------------------------------
// K5: one Stockham DIF stage (inverse sign), batched over the 3 mod-3 lanes.
// Verified by hand at n=4 to produce the natural-order unnormalized IDFT.
// ---------------------------------------------------------------------------
__global__ __launch_bounds__(256) void fft_stage(
    const double2* __restrict__ src, double2* __restrict__ dst, int t)
{
    const int flat = blockIdx.x*256 + threadIdx.x;   // < 98304
    const int batch = flat >> 15;
    const int rem   = flat & 32767;
    const int nt = QN >> t;
    const int st = 1 << t;
    const int p = rem >> t;
    const int q = rem & (st - 1);
    const int base = batch * QN;
    const int i0 = base + q + st*p;
    const double2 a = src[i0], b = src[i0 + 32768];
    double sw, cw; sincos(TWO_PI * (double)p / (double)nt, &sw, &cw);
    double2 o0, o1;
    o0.x = a.x + b.x; o0.y = a.y + b.y;
    const double dr = a.x - b.x, di = a.y - b.y;
    o1.x = dr*cw - di*sw;
    o1.y = dr*sw + di*cw;
    dst[base + q + 2*st*p]      = o0;
    dst[base + q + 2*st*p + st] = o1;
}

// ---------------------------------------------------------------------------
// K6: radix-3 recombine (only m < 65536 needed -> t < 131072), 1/M norm,
// interleaved real output y[2m], y[2m+1], cast to f32.
// ---------------------------------------------------------------------------
__global__ __launch_bounds__(256) void combine_out(
    const double2* __restrict__ F, float* __restrict__ out)
{
    const int m = blockIdx.x*256 + threadIdx.x;  // < 65536
    const double2 F0 = F[m], F1 = F[QN + m], F2 = F[2*QN + m];
    double s1, c1, s2, c2;
    sincos(TWO_PI * (double)m       / (double)MHALF, &s1, &c1);
    sincos(TWO_PI * (double)(2*m)   / (double)MHALF, &s2, &c2);
    const double gr = F0.x + (c1*F1.x - s1*F1.y) + (c2*F2.x - s2*F2.y);
    const double gi = F0.y + (c1*F1.y + s1*F1.x) + (c2*F2.y + s2*F2.x);
    const double inv = 1.0 / (double)MHALF;
    out[2*m]   = (float)(gr * inv);
    out[2*m+1] = (float)(gi * inv);
}

// ---------------------------------------------------------------------------
extern "C" void kernel_launch(void* const* d_in, const int* in_sizes, int n_in,
                              void* d_out, int out_size, void* d_ws, size_t ws_size,
                              hipStream_t stream) {
    const float* base       = (const float*)d_in[0];
    const float* to_off_w   = (const float*)d_in[1];
    const float* split_w    = (const float*)d_in[2];
    const float* split_b    = (const float*)d_in[3];
    const float* atoms      = (const float*)d_in[4];
    const float* to_atoms_w = (const float*)d_in[5];
    const float* to_atoms_b = (const float*)d_in[6];
    const float* to_amp_w   = (const float*)d_in[7];
    const float* to_amp_b   = (const float*)d_in[8];
    float* out = (float*)d_out;

    // workspace layout (~9.72 MB)
    char* ws = (char*)d_ws;
    float*   sF = (float*)(ws + 0);            //    512 B
    float*   xF = (float*)(ws + 512);          //   8192 B
    float*   zf = (float*)(ws + 16384);        // 262144 B -> 278528
    double2* H  = (double2*)(ws + 278528);     // 196609*16 -> 3424272
    double2* Ga = (double2*)(ws + 3424272);    // 196608*16 -> 6570000
    double2* Gb = (double2*)(ws + 6570000);    // 196608*16 -> 9715728

    tree_f32<<<1, 256, 0, stream>>>(base, to_off_w, split_w, split_b, xF, sF);
    events_f32<<<NEV, 256, 0, stream>>>(atoms, to_atoms_w, to_atoms_b,
                                        to_amp_w, to_amp_b, xF, zf);
    forward_spec<<<769, 256, 0, stream>>>(zf, sF, H);
    pack_g<<<768, 256, 0, stream>>>(H, Ga);
    double2* src = Ga; double2* dst = Gb;
    for (int t = 0; t < 16; ++t) {
        fft_stage<<<384, 256, 0, stream>>>(src, dst, t);
        double2* tmp = src; src = dst; dst = tmp;
    }
    // 16 swaps -> result back in Ga (== src)
    combine_out<<<256, 256, 0, stream>>>(src, out);
}

// Round 5
// 300.491 us; speedup vs baseline: 11.9853x; 11.9853x over previous
//
#include <hip/hip_runtime.h>
#include <hip/hip_bf16.h>
#include <math.h>

// Problem constants
constexpr int NSAMP  = 131072;
constexpr int NEV    = 128;
constexpr int ASIZE  = 512;
constexpr int LDIM   = 16;
constexpr int NLAYER = 7;
constexpr int NFFT   = 393216;     // padded FFT length (3*NSAMP)
constexpr int MHALF  = 196608;     // NFFT/2
constexpr int QN     = 65536;      // MHALF/3 (radix-2 FFT length)
constexpr double TWO_PI = 6.283185307179586;

// Pipeline (round-4 PASS baseline, forward transform restructured for speed):
//   f32-faithful front-end (bit-exact bt -> s), f32-quantized phases
//   theta = f32(f32(2k*pi_f32)/196609f * s)  [this creates the ghost field],
//   fp64-accumulated spectra, one inverse real FFT (radix-3 x 16 radix-2
//   Stockham stages, verified).
// Forward now uses k = b + 768*a:  S_e(b+768a) = FFT512_a{ z_e[u]*T_b[u] },
// fused per-block LDS FFT (fp32) + per-bin phase accumulation (fp64 regs).

__device__ __forceinline__ float2 cmulf(float2 a, float2 b) {
    return make_float2(a.x*b.x - a.y*b.y, a.x*b.y + a.y*b.x);
}

// sin/cos of the EXACT value of a float32 phase (magnitude up to ~8e5):
// exact mod-2pi reduction in double via two fmas, then fast f32 sincos.
__device__ __forceinline__ void phase_sc(float th32, float* ps, float* pc) {
    const double th = (double)th32;
    const double n  = rint(th * 0.15915494309189535);
    double r = fma(-n, 6.283185307179586, th);       // th - n*2pi_hi (1 rounding)
    r = fma(-n, 2.4492935982947064e-16, r);          // - n*2pi_lo
    __sincosf((float)r, ps, pc);
}

// ---------------------------------------------------------------------------
// K1: latent tree, strict f32 (sequential dot order, mul+add, no fma).
// ---------------------------------------------------------------------------
__global__ __launch_bounds__(256) void tree_f32(
    const float* __restrict__ base, const float* __restrict__ to_off_w,
    const float* __restrict__ split_w, const float* __restrict__ split_b,
    float* __restrict__ xF, float* __restrict__ sF)
{
    __shared__ float xA[NEV*LDIM], xB[NEV*LDIM], bA[NEV], bB[NEV];
    const int tid = threadIdx.x;
    if (tid < LDIM) xA[tid] = base[tid];
    if (tid == 0) bA[0] = 0.0f;
    __syncthreads();
    float* xi = xA; float* xo = xB; float* bi = bA; float* bo = bB;
    for (int i = 0; i < NLAYER; ++i) {
        const int ein = 1 << i;
        const float scale = 1.0f / (float)(1 << i);      // exact pow2
        for (int idx = tid; idx < ein*32; idx += 256) {
            const int ep = idx >> 5, o2 = idx & 31;
            const float* wr = split_w + (i*32 + o2)*LDIM;
            const float* xr = xi + ep*LDIM;
            float s = __fmul_rn(xr[0], wr[0]);
            for (int l = 1; l < LDIM; ++l)
                s = __fadd_rn(s, __fmul_rn(xr[l], wr[l]));
            s = __fadd_rn(s, split_b[i*32 + o2]);        // bias AFTER dot
            xo[(ep*2 + (o2>>4))*LDIM + (o2&15)] = s;
        }
        for (int idx = tid; idx < ein*2; idx += 256) {
            const int ep = idx >> 1, o = idx & 1;
            const float* wr = to_off_w + (i*2 + o)*LDIM;
            const float* xr = xi + ep*LDIM;
            float v = __fmul_rn(xr[0], wr[0]);
            for (int l = 1; l < LDIM; ++l)
                v = __fadd_rn(v, __fmul_rn(xr[l], wr[l]));
            const float ef = (float)exp(-(double)v);
            const float sg = __fdiv_rn(1.0f, __fadd_rn(1.0f, ef));
            bo[ep*2 + o] = __fadd_rn(bi[ep], __fmul_rn(sg, scale));
        }
        __syncthreads();
        float* t;
        t = xi; xi = xo; xo = t;
        t = bi; bi = bo; bo = t;
    }
    for (int idx = tid; idx < NEV*LDIM; idx += 256) xF[idx] = xi[idx];
    for (int e = tid; e < NEV; e += 256)
        sF[e] = __fmul_rn(__fmul_rn(bi[e], 131072.0f), 0.5f);
}

// ---------------------------------------------------------------------------
// K2: per-event signal, strict f32 chain (mix -> window -> norm -> amp).
// ---------------------------------------------------------------------------
__global__ __launch_bounds__(256) void events_f32(
    const float* __restrict__ atoms, const float* __restrict__ to_atoms_w,
    const float* __restrict__ to_atoms_b, const float* __restrict__ to_amp_w,
    const float* __restrict__ to_amp_b, const float* __restrict__ xF,
    float* __restrict__ zf)
{
    const int e = blockIdx.x;
    const int tid = threadIdx.x;
    __shared__ float mixS[32];
    __shared__ float evS[ASIZE];
    __shared__ double red[256];
    __shared__ float scl[2];
    const float* x = xF + e*LDIM;
    if (tid < 32) {
        const float* wr = to_atoms_w + tid*LDIM;
        float m = __fmul_rn(x[0], wr[0]);
        for (int l = 1; l < LDIM; ++l) m = __fadd_rn(m, __fmul_rn(x[l], wr[l]));
        mixS[tid] = __fadd_rn(m, to_atoms_b[tid]);
    }
    __syncthreads();
    double ss = 0.0;
    for (int u = tid; u < ASIZE; u += 256) {
        float v = __fmul_rn(mixS[0], atoms[u]);
        for (int a = 1; a < 32; ++a)
            v = __fadd_rn(v, __fmul_rn(mixS[a], atoms[a*ASIZE + u]));
        const float ang = __fdiv_rn(__fmul_rn(6.283185307179586f, (float)u), 512.0f);
        const float cw = (float)cos((double)ang);
        const float w  = __fsub_rn(0.54f, __fmul_rn(0.46f, cw));
        v = __fmul_rn(v, w);
        evS[u] = v;
        ss += (double)v * (double)v;
    }
    red[tid] = ss; __syncthreads();
    for (int s = 128; s > 0; s >>= 1) { if (tid < s) red[tid] += red[tid+s]; __syncthreads(); }
    if (tid == 0) {
        const float nf = (float)sqrt(red[0]);
        scl[0] = __fadd_rn(nf, 1e-8f);
        float a = __fmul_rn(x[0], to_amp_w[0]);
        for (int l = 1; l < LDIM; ++l) a = __fadd_rn(a, __fmul_rn(x[l], to_amp_w[l]));
        scl[1] = __fadd_rn(a, to_amp_b[0]);
    }
    __syncthreads();
    const float den = scl[0], amp = scl[1];
    for (int u = tid; u < ASIZE; u += 256)
        zf[e*ASIZE + u] = __fmul_rn(__fdiv_rn(evS[u], den), amp);
}

// ---------------------------------------------------------------------------
// K3 (hot, restructured): fused per-b forward.
// Block b in [0,768): for each event, modulate z_e by T_b[u]=e^{-2pi i b u/N},
// LDS radix-4 Stockham FFT-512 (fp32, natural order; 4 radix-4 stages + final
// radix-2 in registers), then thread `tid` applies phase e^{i theta(e,k)} for
// its bin k = b + 768*tid and accumulates H in fp64 registers.
// Thread 0 of block 0 also handles k = 196608 (bin a=256).
// ---------------------------------------------------------------------------
__global__ __launch_bounds__(256) void forward_fused(
    const float* __restrict__ zf, const float* __restrict__ sF,
    double2* __restrict__ H)
{
    __shared__ float2 A[512], B[512], T[512], W[512];
    __shared__ float sSh[NEV];
    const int b   = blockIdx.x;
    const int tid = threadIdx.x;

    for (int j = tid; j < 512; j += 256) {
        double s1, c1;
        sincos(-TWO_PI * (double)j / 512.0, &s1, &c1);
        W[j] = make_float2((float)c1, (float)s1);
        sincos(-TWO_PI * (double)(b * j) / (double)NFFT, &s1, &c1);
        T[j] = make_float2((float)c1, (float)s1);
    }
    if (tid < NEV) sSh[tid] = sF[tid];
    __syncthreads();

    // f32 phase coefficient chain (bit-identical to np): 2k exact in f32
    const int k1 = b + 768 * tid;                          // <= 196607
    const float c2m = __fdiv_rn(__fmul_rn((float)(2*k1), 3.14159274101257324f),
                                196609.0f);
    const float c2s = __fdiv_rn(__fmul_rn(393216.0f, 3.14159274101257324f),
                                196609.0f);               // k = 196608
    const bool special = (b == 0 && tid == 0);

    double mR = 0.0, mI = 0.0, spR = 0.0, spI = 0.0;

    for (int e = 0; e < NEV; ++e) {
        __syncthreads();                 // all lanes done reading prev buffers
        {
            const float z0 = zf[e*ASIZE + tid];
            const float z1 = zf[e*ASIZE + 256 + tid];
            const float2 t0 = T[tid], t1 = T[tid + 256];
            A[tid]       = make_float2(z0*t0.x, z0*t0.y);
            A[tid + 256] = make_float2(z1*t1.x, z1*t1.y);
        }
        __syncthreads();
        float2* src = A; float2* dst = B;
        #pragma unroll
        for (int s4 = 0; s4 < 4; ++s4) {         // radix-4: st = 1,4,16,64
            const int lg = 2*s4;
            const int st = 1 << lg;
            if (tid < 128) {
                const int q = tid & (st - 1);
                const int p = tid >> lg;
                const float2 a0 = src[tid];
                const float2 a1 = src[tid + 128];
                const float2 a2 = src[tid + 256];
                const float2 a3 = src[tid + 384];
                const float2 t0 = make_float2(a0.x + a2.x, a0.y + a2.y);
                const float2 t1 = make_float2(a0.x - a2.x, a0.y - a2.y);
                const float2 t2 = make_float2(a1.x + a3.x, a1.y + a3.y);
                const float2 t3 = make_float2(a1.x - a3.x, a1.y - a3.y);
                const float2 y0 = make_float2(t0.x + t2.x, t0.y + t2.y);
                const float2 y2 = make_float2(t0.x - t2.x, t0.y - t2.y);
                float2 y1 = make_float2(t1.x + t3.y, t1.y - t3.x);  // t1 - i*t3
                float2 y3 = make_float2(t1.x - t3.y, t1.y + t3.x);  // t1 + i*t3
                const int tw = p << lg;                  // p*st, 3*tw < 512
                y1 = cmulf(y1, W[tw]);
                const float2 y2t = cmulf(y2, W[2*tw]);
                y3 = cmulf(y3, W[3*tw]);
                const int o = q + (p << (lg + 2));       // q + 4*st*p
                dst[o]        = y0;
                dst[o + st]   = y1;
                dst[o + 2*st] = y2t;
                dst[o + 3*st] = y3;
            }
            __syncthreads();
            float2* tt = src; src = dst; dst = tt;
        }
        // final radix-2 (st=256) entirely in registers
        const float2 ra = src[tid];
        const float2 rc = src[tid + 256];
        const float2 S0 = make_float2(ra.x + rc.x, ra.y + rc.y);   // bin a=tid

        {
            const float th = __fmul_rn(c2m, sSh[e]);
            float ps, pc; phase_sc(th, &ps, &pc);
            mR += (double)S0.x * (double)pc - (double)S0.y * (double)ps;
            mI += (double)S0.x * (double)ps + (double)S0.y * (double)pc;
        }
        if (special) {
            const float2 S1 = make_float2(ra.x - rc.x, ra.y - rc.y); // a=256
            const float th = __fmul_rn(c2s, sSh[e]);
            float ps, pc; phase_sc(th, &ps, &pc);
            spR += (double)S1.x * (double)pc - (double)S1.y * (double)ps;
            spI += (double)S1.x * (double)ps + (double)S1.y * (double)pc;
        }
    }

    H[k1] = make_double2(mR, mI);
    if (special) H[MHALF] = make_double2(spR, spI);
}

// ---------------------------------------------------------------------------
// K4: pack Hermitian spectrum (with irfft's Im-drop at DC/Nyquist) into the
// half-size complex sequence G, deinterleaved mod 3 for the radix-3 split.
// ---------------------------------------------------------------------------
__global__ __launch_bounds__(256) void pack_g(
    const double2* __restrict__ H, double2* __restrict__ Ga)
{
    const int k = blockIdx.x*256 + threadIdx.x;   // < 196608
    double2 Hk = H[k], Hm = H[MHALF - k];
    if (k == 0) { Hk.y = 0.0; Hm.y = 0.0; }       // irfft drops these imags
    const double Pr = Hk.x + Hm.x, Pi_ = Hk.y - Hm.y;
    const double Qr = Hk.x - Hm.x, Qi = Hk.y + Hm.y;
    double sw, cw; sincos(TWO_PI * (double)k / (double)NFFT, &sw, &cw);
    const double WQr = cw*Qr - sw*Qi;
    const double WQi = cw*Qi + sw*Qr;
    double2 G;
    G.x = 0.5*(Pr - WQi);
    G.y = 0.5*(Pi_ + WQr);
    Ga[(k % 3)*QN + (k/3)] = G;
}

// ---------------------------------------------------------------------------
// K5: one Stockham DIF stage (inverse sign), batched over the 3 mod-3 lanes.
// ---------------------------------------------------------------------------
__global__ __launch_bounds__(256) void fft_stage(
    const double2* __restrict__ src, double2* __restrict__ dst, int t)
{
    const int flat = blockIdx.x*256 + threadIdx.x;   // < 98304
    const int batch = flat >> 15;
    const int rem   = flat & 32767;
    const int nt = QN >> t;
    const int st = 1 << t;
    const int p = rem >> t;
    const int q = rem & (st - 1);
    const int base = batch * QN;
    const int i0 = base + q + st*p;
    const double2 a = src[i0], b = src[i0 + 32768];
    double sw, cw; sincos(TWO_PI * (double)p / (double)nt, &sw, &cw);
    double2 o0, o1;
    o0.x = a.x + b.x; o0.y = a.y + b.y;
    const double dr = a.x - b.x, di = a.y - b.y;
    o1.x = dr*cw - di*sw;
    o1.y = dr*sw + di*cw;
    dst[base + q + 2*st*p]      = o0;
    dst[base + q + 2*st*p + st] = o1;
}

// ---------------------------------------------------------------------------
// K6: radix-3 recombine, 1/M norm, interleaved real output, cast to f32.
// ---------------------------------------------------------------------------
__global__ __launch_bounds__(256) void combine_out(
    const double2* __restrict__ F, float* __restrict__ out)
{
    const int m = blockIdx.x*256 + threadIdx.x;  // < 65536
    const double2 F0 = F[m], F1 = F[QN + m], F2 = F[2*QN + m];
    double s1, c1, s2, c2;
    sincos(TWO_PI * (double)m       / (double)MHALF, &s1, &c1);
    sincos(TWO_PI * (double)(2*m)   / (double)MHALF, &s2, &c2);
    const double gr = F0.x + (c1*F1.x - s1*F1.y) + (c2*F2.x - s2*F2.y);
    const double gi = F0.y + (c1*F1.y + s1*F1.x) + (c2*F2.y + s2*F2.x);
    const double inv = 1.0 / (double)MHALF;
    out[2*m]   = (float)(gr * inv);
    out[2*m+1] = (float)(gi * inv);
}

// ---------------------------------------------------------------------------
extern "C" void kernel_launch(void* const* d_in, const int* in_sizes, int n_in,
                              void* d_out, int out_size, void* d_ws, size_t ws_size,
                              hipStream_t stream) {
    const float* base       = (const float*)d_in[0];
    const float* to_off_w   = (const float*)d_in[1];
    const float* split_w    = (const float*)d_in[2];
    const float* split_b    = (const float*)d_in[3];
    const float* atoms      = (const float*)d_in[4];
    const float* to_atoms_w = (const float*)d_in[5];
    const float* to_atoms_b = (const float*)d_in[6];
    const float* to_amp_w   = (const float*)d_in[7];
    const float* to_amp_b   = (const float*)d_in[8];
    float* out = (float*)d_out;

    // workspace layout (~9.72 MB)
    char* ws = (char*)d_ws;
    float*   sF = (float*)(ws + 0);            //    512 B
    float*   xF = (float*)(ws + 512);          //   8192 B
    float*   zf = (float*)(ws + 16384);        // 262144 B -> 278528
    double2* H  = (double2*)(ws + 278528);     // 196609*16 -> 3424272
    double2* Ga = (double2*)(ws + 3424272);    // 196608*16 -> 6570000
    double2* Gb = (double2*)(ws + 6570000);    // 196608*16 -> 9715728

    tree_f32<<<1, 256, 0, stream>>>(base, to_off_w, split_w, split_b, xF, sF);
    events_f32<<<NEV, 256, 0, stream>>>(atoms, to_atoms_w, to_atoms_b,
                                        to_amp_w, to_amp_b, xF, zf);
    forward_fused<<<768, 256, 0, stream>>>(zf, sF, H);
    pack_g<<<768, 256, 0, stream>>>(H, Ga);
    double2* src = Ga; double2* dst = Gb;
    for (int t = 0; t < 16; ++t) {
        fft_stage<<<384, 256, 0, stream>>>(src, dst, t);
        double2* tmp = src; src = dst; dst = tmp;
    }
    // 16 swaps -> result back in Ga (== src)
    combine_out<<<256, 256, 0, stream>>>(src, out);
}

// Round 6
// 232.061 us; speedup vs baseline: 15.5195x; 1.2949x over previous
//
#include <hip/hip_runtime.h>
#include <hip/hip_bf16.h>
#include <math.h>

// Problem constants
constexpr int NSAMP  = 131072;
constexpr int NEV    = 128;
constexpr int ASIZE  = 512;
constexpr int LDIM   = 16;
constexpr int NLAYER = 7;
constexpr int NFFT   = 393216;     // padded FFT length (3*NSAMP)
constexpr int MHALF  = 196608;     // NFFT/2
constexpr int QN     = 65536;      // MHALF/3 = 4^8 (radix-4 FFT length)
constexpr double TWO_PI = 6.283185307179586;

// Pipeline: f32-faithful front-end (bit-exact bt -> s), f32-quantized phases
// theta = f32(f32(2k*pi_f32)/196609f * s) [the ghost field], fp64 spectra,
// one inverse real FFT (radix-3 split x 8 radix-4 Stockham stages).
// Forward: k = b + 768a, S_e(b+768a) = FFT512_a{ z_e[u]*T_b[u] }.
// Hermitian trick (z real): FFT upper bins of block b give conj spectra for
// class 768-b -> only b in [0,384] computed (half the FFTs).

__device__ __forceinline__ float2 cmulf(float2 a, float2 b) {
    return make_float2(a.x*b.x - a.y*b.y, a.x*b.y + a.y*b.x);
}

// sin/cos of the EXACT value of a float32 phase (magnitude up to ~8e5):
// exact mod-2pi reduction in double via two fmas, then fast f32 sincos.
__device__ __forceinline__ void phase_sc(float th32, float* ps, float* pc) {
    const double th = (double)th32;
    const double n  = rint(th * 0.15915494309189535);
    double r = fma(-n, 6.283185307179586, th);
    r = fma(-n, 2.4492935982947064e-16, r);
    __sincosf((float)r, ps, pc);
}

// ---------------------------------------------------------------------------
// K1: latent tree, strict f32 (sequential dot order, mul+add, no fma).
// ---------------------------------------------------------------------------
__global__ __launch_bounds__(256) void tree_f32(
    const float* __restrict__ base, const float* __restrict__ to_off_w,
    const float* __restrict__ split_w, const float* __restrict__ split_b,
    float* __restrict__ xF, float* __restrict__ sF)
{
    __shared__ float xA[NEV*LDIM], xB[NEV*LDIM], bA[NEV], bB[NEV];
    const int tid = threadIdx.x;
    if (tid < LDIM) xA[tid] = base[tid];
    if (tid == 0) bA[0] = 0.0f;
    __syncthreads();
    float* xi = xA; float* xo = xB; float* bi = bA; float* bo = bB;
    for (int i = 0; i < NLAYER; ++i) {
        const int ein = 1 << i;
        const float scale = 1.0f / (float)(1 << i);
        for (int idx = tid; idx < ein*32; idx += 256) {
            const int ep = idx >> 5, o2 = idx & 31;
            const float* wr = split_w + (i*32 + o2)*LDIM;
            const float* xr = xi + ep*LDIM;
            float s = __fmul_rn(xr[0], wr[0]);
            for (int l = 1; l < LDIM; ++l)
                s = __fadd_rn(s, __fmul_rn(xr[l], wr[l]));
            s = __fadd_rn(s, split_b[i*32 + o2]);
            xo[(ep*2 + (o2>>4))*LDIM + (o2&15)] = s;
        }
        for (int idx = tid; idx < ein*2; idx += 256) {
            const int ep = idx >> 1, o = idx & 1;
            const float* wr = to_off_w + (i*2 + o)*LDIM;
            const float* xr = xi + ep*LDIM;
            float v = __fmul_rn(xr[0], wr[0]);
            for (int l = 1; l < LDIM; ++l)
                v = __fadd_rn(v, __fmul_rn(xr[l], wr[l]));
            const float ef = (float)exp(-(double)v);
            const float sg = __fdiv_rn(1.0f, __fadd_rn(1.0f, ef));
            bo[ep*2 + o] = __fadd_rn(bi[ep], __fmul_rn(sg, scale));
        }
        __syncthreads();
        float* t;
        t = xi; xi = xo; xo = t;
        t = bi; bi = bo; bo = t;
    }
    for (int idx = tid; idx < NEV*LDIM; idx += 256) xF[idx] = xi[idx];
    for (int e = tid; e < NEV; e += 256)
        sF[e] = __fmul_rn(__fmul_rn(bi[e], 131072.0f), 0.5f);
}

// ---------------------------------------------------------------------------
// K2: per-event signal, strict f32 chain (mix -> window -> norm -> amp).
// ---------------------------------------------------------------------------
__global__ __launch_bounds__(256) void events_f32(
    const float* __restrict__ atoms, const float* __restrict__ to_atoms_w,
    const float* __restrict__ to_atoms_b, const float* __restrict__ to_amp_w,
    const float* __restrict__ to_amp_b, const float* __restrict__ xF,
    float* __restrict__ zf)
{
    const int e = blockIdx.x;
    const int tid = threadIdx.x;
    __shared__ float mixS[32];
    __shared__ float evS[ASIZE];
    __shared__ double red[256];
    __shared__ float scl[2];
    const float* x = xF + e*LDIM;
    if (tid < 32) {
        const float* wr = to_atoms_w + tid*LDIM;
        float m = __fmul_rn(x[0], wr[0]);
        for (int l = 1; l < LDIM; ++l) m = __fadd_rn(m, __fmul_rn(x[l], wr[l]));
        mixS[tid] = __fadd_rn(m, to_atoms_b[tid]);
    }
    __syncthreads();
    double ss = 0.0;
    for (int u = tid; u < ASIZE; u += 256) {
        float v = __fmul_rn(mixS[0], atoms[u]);
        for (int a = 1; a < 32; ++a)
            v = __fadd_rn(v, __fmul_rn(mixS[a], atoms[a*ASIZE + u]));
        const float ang = __fdiv_rn(__fmul_rn(6.283185307179586f, (float)u), 512.0f);
        const float cw = (float)cos((double)ang);
        const float w  = __fsub_rn(0.54f, __fmul_rn(0.46f, cw));
        v = __fmul_rn(v, w);
        evS[u] = v;
        ss += (double)v * (double)v;
    }
    red[tid] = ss; __syncthreads();
    for (int s = 128; s > 0; s >>= 1) { if (tid < s) red[tid] += red[tid+s]; __syncthreads(); }
    if (tid == 0) {
        const float nf = (float)sqrt(red[0]);
        scl[0] = __fadd_rn(nf, 1e-8f);
        float a = __fmul_rn(x[0], to_amp_w[0]);
        for (int l = 1; l < LDIM; ++l) a = __fadd_rn(a, __fmul_rn(x[l], to_amp_w[l]));
        scl[1] = __fadd_rn(a, to_amp_b[0]);
    }
    __syncthreads();
    const float den = scl[0], amp = scl[1];
    for (int u = tid; u < ASIZE; u += 256)
        zf[e*ASIZE + u] = __fmul_rn(__fdiv_rn(evS[u], den), amp);
}

// ---------------------------------------------------------------------------
// K3 (hot): fused forward with Hermitian halving.
// Grid: 385 b-values x 4 event-quarters. Two events in flight per iteration
// (threads <128 own slot 0, >=128 own slot 1). Per event: modulate by T_b,
// radix-4 Stockham FFT-512 (fp32, verified network), then thread tid
// accumulates TWO bins in fp64:
//   k1 = b + 768*tid            from S0 = src[tid] + src[tid+256]
//   k2 = (768-b) + 768*(255-tid) from conj(S1), S1 = src[tid] - src[tid+256]
// (b=0: keep k2 only for tid=0 -> k2=196608; b=384: drop k2.)
// Partials land in H via fp64 agent-scope atomics (H pre-zeroed).
// ---------------------------------------------------------------------------
__global__ __launch_bounds__(256) void forward_conj(
    const float* __restrict__ zf, const float* __restrict__ sF,
    double* __restrict__ Hd)
{
    __shared__ float2 bufs[4*512];          // [A0|B0|A1|B1]
    __shared__ float2 T[512], W[512];
    __shared__ float sSh[32];
    const int b       = blockIdx.x >> 2;    // 0..384
    const int quarter = blockIdx.x & 3;
    const int tid     = threadIdx.x;
    const int lid     = tid & 127;
    const int slot    = tid >> 7;
    float2* pA = bufs + slot*1024;
    float2* pB = pA + 512;
    const int e0 = quarter * 32;

    for (int j = tid; j < 512; j += 256) {
        double s1, c1;
        sincos(-TWO_PI * (double)j / 512.0, &s1, &c1);
        W[j] = make_float2((float)c1, (float)s1);
        sincos(-TWO_PI * (double)(b * j) / (double)NFFT, &s1, &c1);
        T[j] = make_float2((float)c1, (float)s1);
    }
    if (tid < 32) sSh[tid] = sF[e0 + tid];

    // f32 phase coefficient chains (bit-identical to np)
    const int k1 = b + 768 * tid;                       // <= 196224
    const int k2 = (768 - b) + 768 * (255 - tid);       // <= 196608
    const float c2a = __fdiv_rn(__fmul_rn((float)(2*k1), 3.14159274101257324f),
                                196609.0f);
    const float c2b = __fdiv_rn(__fmul_rn((float)(2*k2), 3.14159274101257324f),
                                196609.0f);
    const bool inc2 = (b != 384) && (b != 0 || tid == 0);

    double a1R = 0.0, a1I = 0.0, a2R = 0.0, a2I = 0.0;

    for (int it = 0; it < 16; ++it) {
        const int e = e0 + 2*it + slot;
        __syncthreads();                     // prev readers done with pA
        {
            const float* zp = zf + e*ASIZE;
            #pragma unroll
            for (int j = 0; j < 4; ++j) {
                const int pos = lid + 128*j;
                const float z = zp[pos];
                const float2 t = T[pos];
                pA[pos] = make_float2(z*t.x, z*t.y);
            }
        }
        __syncthreads();
        float2* src = pA; float2* dst = pB;
        #pragma unroll
        for (int s4 = 0; s4 < 4; ++s4) {     // radix-4: st = 1,4,16,64
            const int lg = 2*s4;
            const int st = 1 << lg;
            const int q = lid & (st - 1);
            const int p = lid >> lg;
            const float2 a0 = src[lid];
            const float2 a1 = src[lid + 128];
            const float2 a2 = src[lid + 256];
            const float2 a3 = src[lid + 384];
            const float2 t0 = make_float2(a0.x + a2.x, a0.y + a2.y);
            const float2 t1 = make_float2(a0.x - a2.x, a0.y - a2.y);
            const float2 t2 = make_float2(a1.x + a3.x, a1.y + a3.y);
            const float2 t3 = make_float2(a1.x - a3.x, a1.y - a3.y);
            const float2 y0 = make_float2(t0.x + t2.x, t0.y + t2.y);
            const float2 y2 = make_float2(t0.x - t2.x, t0.y - t2.y);
            float2 y1 = make_float2(t1.x + t3.y, t1.y - t3.x);  // t1 - i*t3
            float2 y3 = make_float2(t1.x - t3.y, t1.y + t3.x);  // t1 + i*t3
            const int tw = p << lg;
            y1 = cmulf(y1, W[tw]);
            const float2 y2t = cmulf(y2, W[2*tw]);
            y3 = cmulf(y3, W[3*tw]);
            const int o = q + (p << (lg + 2));
            dst[o]        = y0;
            dst[o + st]   = y1;
            dst[o + 2*st] = y2t;
            dst[o + 3*st] = y3;
            __syncthreads();
            float2* tt = src; src = dst; dst = tt;
        }
        // final radix-2 for BOTH slots, from LDS (src == pA for each slot)
        #pragma unroll
        for (int s = 0; s < 2; ++s) {
            const float2* sb = bufs + s*1024;
            const float2 ra = sb[tid];
            const float2 rc = sb[tid + 256];
            const float se = sSh[2*it + s];
            {   // k1 from S0 = ra + rc (bin a = tid)
                const float2 S0 = make_float2(ra.x + rc.x, ra.y + rc.y);
                const float th = __fmul_rn(c2a, se);
                float ps, pc; phase_sc(th, &ps, &pc);
                a1R += (double)S0.x*(double)pc - (double)S0.y*(double)ps;
                a1I += (double)S0.x*(double)ps + (double)S0.y*(double)pc;
            }
            if (inc2) {  // k2 from conj(S1), S1 = ra - rc (bin a = tid+256)
                const float2 S1 = make_float2(ra.x - rc.x, ra.y - rc.y);
                const float th = __fmul_rn(c2b, se);
                float ps, pc; phase_sc(th, &ps, &pc);
                a2R += (double)S1.x*(double)pc + (double)S1.y*(double)ps;
                a2I += (double)S1.x*(double)ps - (double)S1.y*(double)pc;
            }
        }
    }

    __hip_atomic_fetch_add(Hd + 2*k1,     a1R, __ATOMIC_RELAXED, __HIP_MEMORY_SCOPE_AGENT);
    __hip_atomic_fetch_add(Hd + 2*k1 + 1, a1I, __ATOMIC_RELAXED, __HIP_MEMORY_SCOPE_AGENT);
    if (inc2) {
        __hip_atomic_fetch_add(Hd + 2*k2,     a2R, __ATOMIC_RELAXED, __HIP_MEMORY_SCOPE_AGENT);
        __hip_atomic_fetch_add(Hd + 2*k2 + 1, a2I, __ATOMIC_RELAXED, __HIP_MEMORY_SCOPE_AGENT);
    }
}

// ---------------------------------------------------------------------------
// K4: pack Hermitian spectrum (with irfft's Im-drop at DC/Nyquist) into the
// half-size complex sequence G, deinterleaved mod 3 for the radix-3 split.
// ---------------------------------------------------------------------------
__global__ __launch_bounds__(256) void pack_g(
    const double2* __restrict__ H, double2* __restrict__ Ga)
{
    const int k = blockIdx.x*256 + threadIdx.x;   // < 196608
    double2 Hk = H[k], Hm = H[MHALF - k];
    if (k == 0) { Hk.y = 0.0; Hm.y = 0.0; }
    const double Pr = Hk.x + Hm.x, Pi_ = Hk.y - Hm.y;
    const double Qr = Hk.x - Hm.x, Qi = Hk.y + Hm.y;
    double sw, cw; sincos(TWO_PI * (double)k / (double)NFFT, &sw, &cw);
    const double WQr = cw*Qr - sw*Qi;
    const double WQi = cw*Qi + sw*Qr;
    double2 G;
    G.x = 0.5*(Pr - WQi);
    G.y = 0.5*(Pi_ + WQr);
    Ga[(k % 3)*QN + (k/3)] = G;
}

// ---------------------------------------------------------------------------
// K5: one inverse radix-4 Stockham stage (composition of two verified
// radix-2 stages; n=4 hand-check OK). QN = 4^8 -> 8 launches.
//   P=A0+A2, Q=A0-A2, R=A1+A3, S=A1-A3, w = e^{+2pi i p/nt}
//   dst[o]=P+R; dst[o+st]=(Q+iS)w; dst[o+2st]=(P-R)w^2; dst[o+3st]=(Q-iS)w^3
// ---------------------------------------------------------------------------
__global__ __launch_bounds__(256) void inv4_stage(
    const double2* __restrict__ src, double2* __restrict__ dst, int t)
{
    const int flat = blockIdx.x*256 + threadIdx.x;   // < 49152
    const int batch = flat / 16384;
    const int rem   = flat & 16383;
    const int lg = 2*t;
    const int st = 1 << lg;
    const int nt = QN >> lg;
    const int p = rem >> lg;
    const int q = rem & (st - 1);
    const int base = batch * QN;
    const int i0 = base + q + st*p;
    const double2 A0 = src[i0];
    const double2 A1 = src[i0 + 16384];
    const double2 A2 = src[i0 + 32768];
    const double2 A3 = src[i0 + 49152];
    const double Pr = A0.x + A2.x, Pi_ = A0.y + A2.y;
    const double Qr = A0.x - A2.x, Qi  = A0.y - A2.y;
    const double Rr = A1.x + A3.x, Ri  = A1.y + A3.y;
    const double Sr = A1.x - A3.x, Si  = A1.y - A3.y;
    double sw, cw; sincos(TWO_PI * (double)p / (double)nt, &sw, &cw);
    const double c2 = cw*cw - sw*sw, s2 = 2.0*cw*sw;          // w^2
    const double c3 = c2*cw - s2*sw, s3 = c2*sw + s2*cw;      // w^3
    const int o = base + q + (p << (lg + 2));
    dst[o] = make_double2(Pr + Rr, Pi_ + Ri);
    const double u1r = Qr - Si, u1i = Qi + Sr;                // Q + iS
    dst[o + st]   = make_double2(u1r*cw - u1i*sw, u1r*sw + u1i*cw);
    const double u2r = Pr - Rr, u2i = Pi_ - Ri;
    dst[o + 2*st] = make_double2(u2r*c2 - u2i*s2, u2r*s2 + u2i*c2);
    const double u3r = Qr + Si, u3i = Qi - Sr;                // Q - iS
    dst[o + 3*st] = make_double2(u3r*c3 - u3i*s3, u3r*s3 + u3i*c3);
}

// ---------------------------------------------------------------------------
// K6: radix-3 recombine, 1/M norm, interleaved real output, cast to f32.
// ---------------------------------------------------------------------------
__global__ __launch_bounds__(256) void combine_out(
    const double2* __restrict__ F, float* __restrict__ out)
{
    const int m = blockIdx.x*256 + threadIdx.x;  // < 65536
    const double2 F0 = F[m], F1 = F[QN + m], F2 = F[2*QN + m];
    double s1, c1, s2, c2;
    sincos(TWO_PI * (double)m     / (double)MHALF, &s1, &c1);
    sincos(TWO_PI * (double)(2*m) / (double)MHALF, &s2, &c2);
    const double gr = F0.x + (c1*F1.x - s1*F1.y) + (c2*F2.x - s2*F2.y);
    const double gi = F0.y + (c1*F1.y + s1*F1.x) + (c2*F2.y + s2*F2.x);
    const double inv = 1.0 / (double)MHALF;
    out[2*m]   = (float)(gr * inv);
    out[2*m+1] = (float)(gi * inv);
}

// ---------------------------------------------------------------------------
extern "C" void kernel_launch(void* const* d_in, const int* in_sizes, int n_in,
                              void* d_out, int out_size, void* d_ws, size_t ws_size,
                              hipStream_t stream) {
    const float* base       = (const float*)d_in[0];
    const float* to_off_w   = (const float*)d_in[1];
    const float* split_w    = (const float*)d_in[2];
    const float* split_b    = (const float*)d_in[3];
    const float* atoms      = (const float*)d_in[4];
    const float* to_atoms_w = (const float*)d_in[5];
    const float* to_atoms_b = (const float*)d_in[6];
    const float* to_amp_w   = (const float*)d_in[7];
    const float* to_amp_b   = (const float*)d_in[8];
    float* out = (float*)d_out;

    // workspace layout (~9.72 MB, proven safe)
    char* ws = (char*)d_ws;
    float*   sF = (float*)(ws + 0);            //    512 B
    float*   xF = (float*)(ws + 512);          //   8192 B
    float*   zf = (float*)(ws + 16384);        // 262144 B -> 278528
    double2* H  = (double2*)(ws + 278528);     // 196609*16 -> 3424272
    double2* Ga = (double2*)(ws + 3424272);    // 196608*16 -> 6570000
    double2* Gb = (double2*)(ws + 6570000);    // 196608*16 -> 9715728

    tree_f32<<<1, 256, 0, stream>>>(base, to_off_w, split_w, split_b, xF, sF);
    events_f32<<<NEV, 256, 0, stream>>>(atoms, to_atoms_w, to_atoms_b,
                                        to_amp_w, to_amp_b, xF, zf);
    hipMemsetAsync(H, 0, 196609 * sizeof(double2), stream);
    forward_conj<<<385*4, 256, 0, stream>>>(zf, sF, (double*)H);
    pack_g<<<768, 256, 0, stream>>>(H, Ga);
    double2* src = Ga; double2* dst = Gb;
    for (int t = 0; t < 8; ++t) {
        inv4_stage<<<192, 256, 0, stream>>>(src, dst, t);
        double2* tmp = src; src = dst; dst = tmp;
    }
    // 8 swaps -> result back in Ga (== src)
    combine_out<<<256, 256, 0, stream>>>(src, out);
}

// Round 7
// 222.360 us; speedup vs baseline: 16.1966x; 1.0436x over previous
//
#include <hip/hip_runtime.h>
#include <hip/hip_bf16.h>
#include <math.h>

// Problem constants
constexpr int NSAMP  = 131072;
constexpr int NEV    = 128;
constexpr int ASIZE  = 512;
constexpr int LDIM   = 16;
constexpr int NLAYER = 7;
constexpr int NFFT   = 393216;     // padded FFT length (3*NSAMP)
constexpr int MHALF  = 196608;     // NFFT/2
constexpr int QN     = 65536;      // MHALF/3 = 256*256
constexpr double TWO_PI = 6.283185307179586;

// Pipeline: f32-faithful front-end (bit-exact bt -> s), f32-quantized phases
// theta = f32(f32(2k*pi_f32)/196609f * s) [the ghost field], fp64 spectra,
// inverse real FFT = radix-3 split x (256x256 four-step, fp64).
// Forward: k = b + 768a, S_e(b+768a) = FFT512_a{ z_e[u]*T_b[u] }; Hermitian
// trick -> b in [0,384]. Wave-private LDS FFT (no block barriers in loop).

__device__ __forceinline__ float2 cmulf(float2 a, float2 b) {
    return make_float2(a.x*b.x - a.y*b.y, a.x*b.y + a.y*b.x);
}

// sin/cos of the EXACT value of a float32 phase (magnitude up to ~8e5):
// exact mod-2pi reduction in double via two fmas, then fast f32 sincos.
__device__ __forceinline__ void phase_sc(float th32, float* ps, float* pc) {
    const double th = (double)th32;
    const double n  = rint(th * 0.15915494309189535);
    double r = fma(-n, 6.283185307179586, th);
    r = fma(-n, 2.4492935982947064e-16, r);
    __sincosf((float)r, ps, pc);
}

// ---------------------------------------------------------------------------
// K1: latent tree, strict f32 (sequential dot order, mul+add, no fma).
// ---------------------------------------------------------------------------
__global__ __launch_bounds__(256) void tree_f32(
    const float* __restrict__ base, const float* __restrict__ to_off_w,
    const float* __restrict__ split_w, const float* __restrict__ split_b,
    float* __restrict__ xF, float* __restrict__ sF)
{
    __shared__ float xA[NEV*LDIM], xB[NEV*LDIM], bA[NEV], bB[NEV];
    const int tid = threadIdx.x;
    if (tid < LDIM) xA[tid] = base[tid];
    if (tid == 0) bA[0] = 0.0f;
    __syncthreads();
    float* xi = xA; float* xo = xB; float* bi = bA; float* bo = bB;
    for (int i = 0; i < NLAYER; ++i) {
        const int ein = 1 << i;
        const float scale = 1.0f / (float)(1 << i);
        for (int idx = tid; idx < ein*32; idx += 256) {
            const int ep = idx >> 5, o2 = idx & 31;
            const float* wr = split_w + (i*32 + o2)*LDIM;
            const float* xr = xi + ep*LDIM;
            float s = __fmul_rn(xr[0], wr[0]);
            for (int l = 1; l < LDIM; ++l)
                s = __fadd_rn(s, __fmul_rn(xr[l], wr[l]));
            s = __fadd_rn(s, split_b[i*32 + o2]);
            xo[(ep*2 + (o2>>4))*LDIM + (o2&15)] = s;
        }
        for (int idx = tid; idx < ein*2; idx += 256) {
            const int ep = idx >> 1, o = idx & 1;
            const float* wr = to_off_w + (i*2 + o)*LDIM;
            const float* xr = xi + ep*LDIM;
            float v = __fmul_rn(xr[0], wr[0]);
            for (int l = 1; l < LDIM; ++l)
                v = __fadd_rn(v, __fmul_rn(xr[l], wr[l]));
            const float ef = (float)exp(-(double)v);
            const float sg = __fdiv_rn(1.0f, __fadd_rn(1.0f, ef));
            bo[ep*2 + o] = __fadd_rn(bi[ep], __fmul_rn(sg, scale));
        }
        __syncthreads();
        float* t;
        t = xi; xi = xo; xo = t;
        t = bi; bi = bo; bo = t;
    }
    for (int idx = tid; idx < NEV*LDIM; idx += 256) xF[idx] = xi[idx];
    for (int e = tid; e < NEV; e += 256)
        sF[e] = __fmul_rn(__fmul_rn(bi[e], 131072.0f), 0.5f);
}

// ---------------------------------------------------------------------------
// K2: per-event signal, strict f32 chain (mix -> window -> norm -> amp).
// ---------------------------------------------------------------------------
__global__ __launch_bounds__(256) void events_f32(
    const float* __restrict__ atoms, const float* __restrict__ to_atoms_w,
    const float* __restrict__ to_atoms_b, const float* __restrict__ to_amp_w,
    const float* __restrict__ to_amp_b, const float* __restrict__ xF,
    float* __restrict__ zf)
{
    const int e = blockIdx.x;
    const int tid = threadIdx.x;
    __shared__ float mixS[32];
    __shared__ float evS[ASIZE];
    __shared__ double red[256];
    __shared__ float scl[2];
    const float* x = xF + e*LDIM;
    if (tid < 32) {
        const float* wr = to_atoms_w + tid*LDIM;
        float m = __fmul_rn(x[0], wr[0]);
        for (int l = 1; l < LDIM; ++l) m = __fadd_rn(m, __fmul_rn(x[l], wr[l]));
        mixS[tid] = __fadd_rn(m, to_atoms_b[tid]);
    }
    __syncthreads();
    double ss = 0.0;
    for (int u = tid; u < ASIZE; u += 256) {
        float v = __fmul_rn(mixS[0], atoms[u]);
        for (int a = 1; a < 32; ++a)
            v = __fadd_rn(v, __fmul_rn(mixS[a], atoms[a*ASIZE + u]));
        const float ang = __fdiv_rn(__fmul_rn(6.283185307179586f, (float)u), 512.0f);
        const float cw = (float)cos((double)ang);
        const float w  = __fsub_rn(0.54f, __fmul_rn(0.46f, cw));
        v = __fmul_rn(v, w);
        evS[u] = v;
        ss += (double)v * (double)v;
    }
    red[tid] = ss; __syncthreads();
    for (int s = 128; s > 0; s >>= 1) { if (tid < s) red[tid] += red[tid+s]; __syncthreads(); }
    if (tid == 0) {
        const float nf = (float)sqrt(red[0]);
        scl[0] = __fadd_rn(nf, 1e-8f);
        float a = __fmul_rn(x[0], to_amp_w[0]);
        for (int l = 1; l < LDIM; ++l) a = __fadd_rn(a, __fmul_rn(x[l], to_amp_w[l]));
        scl[1] = __fadd_rn(a, to_amp_b[0]);
    }
    __syncthreads();
    const float den = scl[0], amp = scl[1];
    for (int u = tid; u < ASIZE; u += 256)
        zf[e*ASIZE + u] = __fmul_rn(__fdiv_rn(evS[u], den), amp);
}

// ---------------------------------------------------------------------------
// K3 (hot): barrier-free forward. Grid: 385 b x 4 event-quarters.
// Each wave owns a private ping-pong LDS buffer and 8 events; per event:
// modulate by T_b, radix-4 Stockham FFT-512 (fp32, verified math, 2
// butterflies/lane/stage, NO block barriers - intra-wave LDS is in-order),
// then each lane accumulates 4 a-bins x (k1,k2) in fp64 registers:
//   k1 = b + 768*a  (from S0 = src[a]+src[a+256])
//   k2 = (768-b) + 768*(255-a)  (from conj(S1), S1 = src[a]-src[a+256])
// End: block LDS reduction over the 4 waves, 1024 fp64 atomics into H.
// ---------------------------------------------------------------------------
__global__ __launch_bounds__(256, 4) void forward_wave(
    const float* __restrict__ zf, const float* __restrict__ sF,
    double* __restrict__ Hd)
{
    __shared__ double redS[4096];       // 32 KB: FFT buffers, then reduction
    __shared__ float2 T[512];           // 4 KB
    __shared__ float2 W[384];           // 3 KB
    __shared__ float sSh[32];
    const int b       = blockIdx.x >> 2;    // 0..384
    const int quarter = blockIdx.x & 3;
    const int tid  = threadIdx.x;
    const int wave = tid >> 6, lane = tid & 63;
    float2* bufs = (float2*)redS;
    float2* pA = bufs + wave*1024;
    float2* pB = pA + 512;
    const int e0 = quarter * 32;

    for (int j = tid; j < 512; j += 256) {
        double s1, c1;
        if (j < 384) {
            sincos(-TWO_PI * (double)j / 512.0, &s1, &c1);
            W[j] = make_float2((float)c1, (float)s1);
        }
        sincos(-TWO_PI * (double)(b * j) / (double)NFFT, &s1, &c1);
        T[j] = make_float2((float)c1, (float)s1);
    }
    if (tid < 32) sSh[tid] = sF[e0 + tid];
    __syncthreads();

    // per-lane bins and f32 phase coefficient chains (bit-identical to np)
    float c2a[4], c2b[4];
    #pragma unroll
    for (int j = 0; j < 4; ++j) {
        const int a  = lane + 64*j;
        const int k1 = b + 768*a;
        const int k2 = (768 - b) + 768*(255 - a);
        c2a[j] = __fdiv_rn(__fmul_rn((float)(2*k1), 3.14159274101257324f), 196609.0f);
        c2b[j] = __fdiv_rn(__fmul_rn((float)(2*k2), 3.14159274101257324f), 196609.0f);
    }

    double a1R[4] = {0,0,0,0}, a1I[4] = {0,0,0,0};
    double a2R[4] = {0,0,0,0}, a2I[4] = {0,0,0,0};

    for (int it = 0; it < 8; ++it) {
        const int e = e0 + wave*8 + it;
        const float* zp = zf + e*ASIZE;
        #pragma unroll
        for (int r = 0; r < 8; ++r) {
            const int pos = lane + 64*r;
            const float z = zp[pos];
            const float2 t = T[pos];
            pA[pos] = make_float2(z*t.x, z*t.y);
        }
        float2* src = pA; float2* dst = pB;
        #pragma unroll
        for (int s4 = 0; s4 < 4; ++s4) {    // radix-4: st = 1,4,16,64
            const int lg = 2*s4;
            const int st = 1 << lg;
            #pragma unroll
            for (int h = 0; h < 2; ++h) {
                const int idx = lane + 64*h;       // [0,128)
                const int q = idx & (st - 1);
                const int p = idx >> lg;
                const float2 A0 = src[idx];
                const float2 A1 = src[idx + 128];
                const float2 A2 = src[idx + 256];
                const float2 A3 = src[idx + 384];
                const float2 t0 = make_float2(A0.x + A2.x, A0.y + A2.y);
                const float2 t1 = make_float2(A0.x - A2.x, A0.y - A2.y);
                const float2 t2 = make_float2(A1.x + A3.x, A1.y + A3.y);
                const float2 t3 = make_float2(A1.x - A3.x, A1.y - A3.y);
                const float2 y0 = make_float2(t0.x + t2.x, t0.y + t2.y);
                const float2 y2 = make_float2(t0.x - t2.x, t0.y - t2.y);
                float2 y1 = make_float2(t1.x + t3.y, t1.y - t3.x);  // t1 - i*t3
                float2 y3 = make_float2(t1.x - t3.y, t1.y + t3.x);  // t1 + i*t3
                const int tw = p << lg;
                y1 = cmulf(y1, W[tw]);
                const float2 y2t = cmulf(y2, W[2*tw]);
                y3 = cmulf(y3, W[3*tw]);
                const int o = q + (p << (lg + 2));
                dst[o]        = y0;
                dst[o + st]   = y1;
                dst[o + 2*st] = y2t;
                dst[o + 3*st] = y3;
            }
            float2* tt = src; src = dst; dst = tt;
        }
        // final radix-2 + phase accumulation (src == pA after 4 swaps)
        const float se = sSh[wave*8 + it];
        #pragma unroll
        for (int j = 0; j < 4; ++j) {
            const int a = lane + 64*j;
            const float2 ra = src[a];
            const float2 rc = src[a + 256];
            {   // k1 from S0 = ra + rc (bin a)
                const float2 S0 = make_float2(ra.x + rc.x, ra.y + rc.y);
                const float th = __fmul_rn(c2a[j], se);
                float ps, pc; phase_sc(th, &ps, &pc);
                a1R[j] += (double)S0.x*(double)pc - (double)S0.y*(double)ps;
                a1I[j] += (double)S0.x*(double)ps + (double)S0.y*(double)pc;
            }
            if ((b != 384) && (b != 0 || a == 0)) {  // k2 from conj(S1)
                const float2 S1 = make_float2(ra.x - rc.x, ra.y - rc.y);
                const float th = __fmul_rn(c2b[j], se);
                float ps, pc; phase_sc(th, &ps, &pc);
                a2R[j] += (double)S1.x*(double)pc + (double)S1.y*(double)ps;
                a2I[j] += (double)S1.x*(double)ps - (double)S1.y*(double)pc;
            }
        }
    }

    // block reduction over the 4 waves (same atomic count as before: 1024)
    __syncthreads();
    {
        double* my = redS + (wave*64 + lane)*16;
        #pragma unroll
        for (int j = 0; j < 4; ++j) {
            my[4*j + 0] = a1R[j]; my[4*j + 1] = a1I[j];
            my[4*j + 2] = a2R[j]; my[4*j + 3] = a2I[j];
        }
    }
    __syncthreads();
    {
        const int lane_s = tid >> 2, jm = tid & 3;
        double v0 = 0, v1 = 0, v2 = 0, v3 = 0;
        #pragma unroll
        for (int w = 0; w < 4; ++w) {
            const double* p = redS + ((w*64 + lane_s)*16 + jm*4);
            v0 += p[0]; v1 += p[1]; v2 += p[2]; v3 += p[3];
        }
        const int as = lane_s + 64*jm;
        const int k1 = b + 768*as;
        const int k2 = (768 - b) + 768*(255 - as);
        __hip_atomic_fetch_add(Hd + 2*k1,     v0, __ATOMIC_RELAXED, __HIP_MEMORY_SCOPE_AGENT);
        __hip_atomic_fetch_add(Hd + 2*k1 + 1, v1, __ATOMIC_RELAXED, __HIP_MEMORY_SCOPE_AGENT);
        if ((b != 384) && (b != 0 || as == 0)) {
            __hip_atomic_fetch_add(Hd + 2*k2,     v2, __ATOMIC_RELAXED, __HIP_MEMORY_SCOPE_AGENT);
            __hip_atomic_fetch_add(Hd + 2*k2 + 1, v3, __ATOMIC_RELAXED, __HIP_MEMORY_SCOPE_AGENT);
        }
    }
}

// ---------------------------------------------------------------------------
// K4: inverse four-step, stage A. Job (l, j1): pack G inline from H at
// k = 3*j1 + l + 768*j2, inverse radix-4 FFT-256 over j2 (fp64, verified
// butterfly), twiddle e^{+2pi i j1 m1/65536}, coalesced store to Yg.
// 4 jobs per block, one wave each -> NO barriers.
// ---------------------------------------------------------------------------
__global__ __launch_bounds__(256) void inv_a(
    const double2* __restrict__ H, double2* __restrict__ Yg)
{
    __shared__ double2 buf[4][512];   // per-job ping-pong (A=[0,256), B=[256,512))
    const int tid = threadIdx.x;
    const int jj = tid >> 6, t = tid & 63;
    const int job = blockIdx.x*4 + jj;        // 0..767
    const int l = job >> 8, j1 = job & 255;
    const int k0 = 3*j1 + l;
    double2* A = buf[jj];
    double2* B = A + 256;

    #pragma unroll
    for (int r = 0; r < 4; ++r) {
        const int j2 = t + 64*r;
        const int k = k0 + 768*j2;            // <= 196607
        double2 Hk = H[k], Hm = H[MHALF - k];
        if (k == 0) { Hk.y = 0.0; Hm.y = 0.0; }   // irfft drops these imags
        const double Pr = Hk.x + Hm.x, Pi_ = Hk.y - Hm.y;
        const double Qr = Hk.x - Hm.x, Qi = Hk.y + Hm.y;
        double sw, cw; sincos(TWO_PI * (double)k / (double)NFFT, &sw, &cw);
        const double WQr = cw*Qr - sw*Qi;
        const double WQi = cw*Qi + sw*Qr;
        A[j2] = make_double2(0.5*(Pr - WQi), 0.5*(Pi_ + WQr));
    }

    double2* src = A; double2* dst = B;
    #pragma unroll
    for (int s4 = 0; s4 < 4; ++s4) {          // st = 1,4,16,64
        const int lg = 2*s4;
        const int st = 1 << lg;
        const int nt = 256 >> lg;
        const int q = t & (st - 1), p = t >> lg;
        const double2 A0 = src[t];
        const double2 A1 = src[t + 64];
        const double2 A2 = src[t + 128];
        const double2 A3 = src[t + 192];
        const double Pr = A0.x + A2.x, Pi_ = A0.y + A2.y;
        const double Qr = A0.x - A2.x, Qi  = A0.y - A2.y;
        const double Rr = A1.x + A3.x, Ri  = A1.y + A3.y;
        const double Sr = A1.x - A3.x, Si  = A1.y - A3.y;
        double sw, cw; sincos(TWO_PI * (double)p / (double)nt, &sw, &cw);
        const double c2 = cw*cw - sw*sw, s2 = 2.0*cw*sw;
        const double c3 = c2*cw - s2*sw, s3 = c2*sw + s2*cw;
        const int o = q + (p << (lg + 2));
        dst[o] = make_double2(Pr + Rr, Pi_ + Ri);
        const double u1r = Qr - Si, u1i = Qi + Sr;
        dst[o + st]   = make_double2(u1r*cw - u1i*sw, u1r*sw + u1i*cw);
        const double u2r = Pr - Rr, u2i = Pi_ - Ri;
        dst[o + 2*st] = make_double2(u2r*c2 - u2i*s2, u2r*s2 + u2i*c2);
        const double u3r = Qr + Si, u3i = Qi - Sr;
        dst[o + 3*st] = make_double2(u3r*c3 - u3i*s3, u3r*s3 + u3i*c3);
        double2* tt = src; src = dst; dst = tt;
    }
    // src == A, natural order m1; apply twiddle and store
    #pragma unroll
    for (int r = 0; r < 4; ++r) {
        const int m1 = t + 64*r;
        const double2 v = src[m1];
        double sw, cw; sincos(TWO_PI * (double)(j1*m1) / 65536.0, &sw, &cw);
        Yg[job*256 + m1] = make_double2(v.x*cw - v.y*sw, v.x*sw + v.y*cw);
    }
}

// ---------------------------------------------------------------------------
// K5: inverse four-step, stage B + radix-3 combine + output cast.
// Block per m1: 3 jobs (lanes l=0,1,2 on waves 0-2), each gathers
// Yt[l][j1][m1] over j1, inverse radix-4 FFT-256 over j1 -> X_l[m2].
// Then all 256 threads combine m = m1 + 256*m2 and write out.
// ---------------------------------------------------------------------------
__global__ __launch_bounds__(256) void inv_b(
    const double2* __restrict__ Yg, float* __restrict__ out)
{
    __shared__ double2 buf[3][512];
    const int m1 = blockIdx.x;
    const int tid = threadIdx.x;
    const int l = tid >> 6, t = tid & 63;

    if (l < 3) {
        double2* A = buf[l];
        double2* B = A + 256;
        #pragma unroll
        for (int r = 0; r < 4; ++r) {
            const int j1 = t + 64*r;
            A[j1] = Yg[(l*256 + j1)*256 + m1];
        }
        double2* src = A; double2* dst = B;
        #pragma unroll
        for (int s4 = 0; s4 < 4; ++s4) {
            const int lg = 2*s4;
            const int st = 1 << lg;
            const int nt = 256 >> lg;
            const int q = t & (st - 1), p = t >> lg;
            const double2 A0 = src[t];
            const double2 A1 = src[t + 64];
            const double2 A2 = src[t + 128];
            const double2 A3 = src[t + 192];
            const double Pr = A0.x + A2.x, Pi_ = A0.y + A2.y;
            const double Qr = A0.x - A2.x, Qi  = A0.y - A2.y;
            const double Rr = A1.x + A3.x, Ri  = A1.y + A3.y;
            const double Sr = A1.x - A3.x, Si  = A1.y - A3.y;
            double sw, cw; sincos(TWO_PI * (double)p / (double)nt, &sw, &cw);
            const double c2 = cw*cw - sw*sw, s2 = 2.0*cw*sw;
            const double c3 = c2*cw - s2*sw, s3 = c2*sw + s2*cw;
            const int o = q + (p << (lg + 2));
            dst[o] = make_double2(Pr + Rr, Pi_ + Ri);
            const double u1r = Qr - Si, u1i = Qi + Sr;
            dst[o + st]   = make_double2(u1r*cw - u1i*sw, u1r*sw + u1i*cw);
            const double u2r = Pr - Rr, u2i = Pi_ - Ri;
            dst[o + 2*st] = make_double2(u2r*c2 - u2i*s2, u2r*s2 + u2i*c2);
            const double u3r = Qr + Si, u3i = Qi - Sr;
            dst[o + 3*st] = make_double2(u3r*c3 - u3i*s3, u3r*s3 + u3i*c3);
            double2* tt = src; src = dst; dst = tt;
        }
        // result natural order in A == buf[l][0..255]
    }
    __syncthreads();

    const int m2 = tid;
    const int m = m1 + 256*m2;                 // < 65536*... (m < QN)
    const double2 F0 = buf[0][m2], F1 = buf[1][m2], F2 = buf[2][m2];
    double s1, c1; sincos(TWO_PI * (double)m / (double)MHALF, &s1, &c1);
    const double c2 = c1*c1 - s1*s1, s2 = 2.0*s1*c1;
    const double gr = F0.x + (c1*F1.x - s1*F1.y) + (c2*F2.x - s2*F2.y);
    const double gi = F0.y + (c1*F1.y + s1*F1.x) + (c2*F2.y + s2*F2.x);
    const double inv = 1.0 / (double)MHALF;
    out[2*m]     = (float)(gr * inv);
    out[2*m + 1] = (float)(gi * inv);
}

// ---------------------------------------------------------------------------
extern "C" void kernel_launch(void* const* d_in, const int* in_sizes, int n_in,
                              void* d_out, int out_size, void* d_ws, size_t ws_size,
                              hipStream_t stream) {
    const float* base       = (const float*)d_in[0];
    const float* to_off_w   = (const float*)d_in[1];
    const float* split_w    = (const float*)d_in[2];
    const float* split_b    = (const float*)d_in[3];
    const float* atoms      = (const float*)d_in[4];
    const float* to_atoms_w = (const float*)d_in[5];
    const float* to_atoms_b = (const float*)d_in[6];
    const float* to_amp_w   = (const float*)d_in[7];
    const float* to_amp_b   = (const float*)d_in[8];
    float* out = (float*)d_out;

    // workspace layout (~6.6 MB, within proven-safe bounds)
    char* ws = (char*)d_ws;
    float*   sF = (float*)(ws + 0);            //    512 B
    float*   xF = (float*)(ws + 512);          //   8192 B
    float*   zf = (float*)(ws + 16384);        // 262144 B -> 278528
    double2* H  = (double2*)(ws + 278528);     // 196609*16 -> 3424272
    double2* Yg = (double2*)(ws + 3424272);    // 196608*16 -> 6570000

    tree_f32<<<1, 256, 0, stream>>>(base, to_off_w, split_w, split_b, xF, sF);
    events_f32<<<NEV, 256, 0, stream>>>(atoms, to_atoms_w, to_atoms_b,
                                        to_amp_w, to_amp_b, xF, zf);
    hipMemsetAsync(H, 0, 196609 * sizeof(double2), stream);
    forward_wave<<<385*4, 256, 0, stream>>>(zf, sF, (double*)H);
    inv_a<<<192, 256, 0, stream>>>(H, Yg);
    inv_b<<<256, 256, 0, stream>>>(Yg, out);
}

// Round 8
// 146.421 us; speedup vs baseline: 24.5967x; 1.5186x over previous
//
#include <hip/hip_runtime.h>
#include <hip/hip_bf16.h>
#include <math.h>

// Problem constants
constexpr int NSAMP  = 131072;
constexpr int NEV    = 128;
constexpr int ASIZE  = 512;
constexpr int LDIM   = 16;
constexpr int NLAYER = 7;
constexpr int NFFT   = 393216;     // padded FFT length (3*NSAMP)
constexpr int MHALF  = 196608;     // NFFT/2
constexpr int QN     = 65536;      // MHALF/3 = 256*256
constexpr double TWO_PI = 6.283185307179586;

// Pipeline: f32-faithful front-end (bit-exact bt -> s), f32-quantized phases
// theta = f32(f32(2k*pi_f32)/196609f * s), fp64-ish spectra, inverse real FFT
// = radix-3 split x (256x256 four-step, fp64 with twiddle tables).
// Forward: k = b + 768a, S_e(b+768a) = FFT512_a{ z_e[u]*T_b[u] }; Hermitian
// trick -> b in [0,384]. FFT-512 = 3 in-place radix-8 stages, wave-private,
// register-staged (whole-wave reads precede writes; same-wave DS ordering
// empirically validated by R7). H stored as 4 f32 quarter-partials, class-
// contiguous (no atomics, no memset); inv_a sums quarters on read.

__device__ __forceinline__ float2 cmulf(float2 a, float2 b) {
    return make_float2(a.x*b.x - a.y*b.y, a.x*b.y + a.y*b.x);
}
__device__ __forceinline__ float2 CADD(float2 a, float2 b){ return make_float2(a.x+b.x, a.y+b.y); }
__device__ __forceinline__ float2 CSUB(float2 a, float2 b){ return make_float2(a.x-b.x, a.y-b.y); }

// sin/cos of the EXACT value of a float32 phase (magnitude up to ~8e5):
// exact mod-2pi reduction in double via two fmas, then fast f32 sincos.
__device__ __forceinline__ void phase_sc(float th32, float* ps, float* pc) {
    const double th = (double)th32;
    const double n  = rint(th * 0.15915494309189535);
    double r = fma(-n, 6.283185307179586, th);
    r = fma(-n, 2.4492935982947064e-16, r);
    __sincosf((float)r, ps, pc);
}

// forward DFT-8 on registers (verified vs delta inputs by hand)
#define RT2 0.70710678118654752f
#define DFT8F(A0,A1,A2,A3,A4,A5,A6,A7, X0,X1,X2,X3,X4,X5,X6,X7) { \
  float2 b0=CADD(A0,A4), b1=CADD(A1,A5), b2=CADD(A2,A6), b3=CADD(A3,A7); \
  float2 c0=CSUB(A0,A4); \
  float2 d1=CSUB(A1,A5), d2=CSUB(A2,A6), d3=CSUB(A3,A7); \
  float2 c1=make_float2((d1.x+d1.y)*RT2, (d1.y-d1.x)*RT2); \
  float2 c2=make_float2(d2.y, -d2.x); \
  float2 c3=make_float2((d3.y-d3.x)*RT2, -(d3.x+d3.y)*RT2); \
  float2 t0=CADD(b0,b2), t1=CSUB(b0,b2), t2=CADD(b1,b3), t3=CSUB(b1,b3); \
  X0=CADD(t0,t2); X4=CSUB(t0,t2); \
  X2=make_float2(t1.x+t3.y, t1.y-t3.x); X6=make_float2(t1.x-t3.y, t1.y+t3.x); \
  t0=CADD(c0,c2); t1=CSUB(c0,c2); t2=CADD(c1,c3); t3=CSUB(c1,c3); \
  X1=CADD(t0,t2); X5=CSUB(t0,t2); \
  X3=make_float2(t1.x+t3.y, t1.y-t3.x); X7=make_float2(t1.x-t3.y, t1.y+t3.x); \
}

// ---------------------------------------------------------------------------
// K0: fp64 twiddle tables for the inverse chain.
// ---------------------------------------------------------------------------
__global__ __launch_bounds__(256) void twiddles(
    double2* __restrict__ Tw256, double2* __restrict__ Tw512,
    double2* __restrict__ Tw768, double2* __restrict__ Tw64k)
{
    const int t = threadIdx.x;
    double s, c;
    sincos(TWO_PI*(double)t/256.0,   &s, &c); Tw256[t] = make_double2(c, s);
    sincos(TWO_PI*(double)t/512.0,   &s, &c); Tw512[t] = make_double2(c, s);
    sincos(TWO_PI*(double)t/768.0,   &s, &c); Tw768[t] = make_double2(c, s);
    sincos(TWO_PI*(double)t/65536.0, &s, &c); Tw64k[t] = make_double2(c, s);
}

// ---------------------------------------------------------------------------
// K1: latent tree, strict f32 (sequential dot order, mul+add, no fma).
// ---------------------------------------------------------------------------
__global__ __launch_bounds__(256) void tree_f32(
    const float* __restrict__ base, const float* __restrict__ to_off_w,
    const float* __restrict__ split_w, const float* __restrict__ split_b,
    float* __restrict__ xF, float* __restrict__ sF)
{
    __shared__ float xA[NEV*LDIM], xB[NEV*LDIM], bA[NEV], bB[NEV];
    const int tid = threadIdx.x;
    if (tid < LDIM) xA[tid] = base[tid];
    if (tid == 0) bA[0] = 0.0f;
    __syncthreads();
    float* xi = xA; float* xo = xB; float* bi = bA; float* bo = bB;
    for (int i = 0; i < NLAYER; ++i) {
        const int ein = 1 << i;
        const float scale = 1.0f / (float)(1 << i);
        for (int idx = tid; idx < ein*32; idx += 256) {
            const int ep = idx >> 5, o2 = idx & 31;
            const float* wr = split_w + (i*32 + o2)*LDIM;
            const float* xr = xi + ep*LDIM;
            float s = __fmul_rn(xr[0], wr[0]);
            for (int l = 1; l < LDIM; ++l)
                s = __fadd_rn(s, __fmul_rn(xr[l], wr[l]));
            s = __fadd_rn(s, split_b[i*32 + o2]);
            xo[(ep*2 + (o2>>4))*LDIM + (o2&15)] = s;
        }
        for (int idx = tid; idx < ein*2; idx += 256) {
            const int ep = idx >> 1, o = idx & 1;
            const float* wr = to_off_w + (i*2 + o)*LDIM;
            const float* xr = xi + ep*LDIM;
            float v = __fmul_rn(xr[0], wr[0]);
            for (int l = 1; l < LDIM; ++l)
                v = __fadd_rn(v, __fmul_rn(xr[l], wr[l]));
            const float ef = (float)exp(-(double)v);
            const float sg = __fdiv_rn(1.0f, __fadd_rn(1.0f, ef));
            bo[ep*2 + o] = __fadd_rn(bi[ep], __fmul_rn(sg, scale));
        }
        __syncthreads();
        float* t;
        t = xi; xi = xo; xo = t;
        t = bi; bi = bo; bo = t;
    }
    for (int idx = tid; idx < NEV*LDIM; idx += 256) xF[idx] = xi[idx];
    for (int e = tid; e < NEV; e += 256)
        sF[e] = __fmul_rn(__fmul_rn(bi[e], 131072.0f), 0.5f);
}

// ---------------------------------------------------------------------------
// K2: per-event signal, strict f32 chain (mix -> window -> norm -> amp).
// ---------------------------------------------------------------------------
__global__ __launch_bounds__(256) void events_f32(
    const float* __restrict__ atoms, const float* __restrict__ to_atoms_w,
    const float* __restrict__ to_atoms_b, const float* __restrict__ to_amp_w,
    const float* __restrict__ to_amp_b, const float* __restrict__ xF,
    float* __restrict__ zf)
{
    const int e = blockIdx.x;
    const int tid = threadIdx.x;
    __shared__ float mixS[32];
    __shared__ float evS[ASIZE];
    __shared__ double red[256];
    __shared__ float scl[2];
    const float* x = xF + e*LDIM;
    if (tid < 32) {
        const float* wr = to_atoms_w + tid*LDIM;
        float m = __fmul_rn(x[0], wr[0]);
        for (int l = 1; l < LDIM; ++l) m = __fadd_rn(m, __fmul_rn(x[l], wr[l]));
        mixS[tid] = __fadd_rn(m, to_atoms_b[tid]);
    }
    __syncthreads();
    double ss = 0.0;
    for (int u = tid; u < ASIZE; u += 256) {
        float v = __fmul_rn(mixS[0], atoms[u]);
        for (int a = 1; a < 32; ++a)
            v = __fadd_rn(v, __fmul_rn(mixS[a], atoms[a*ASIZE + u]));
        const float ang = __fdiv_rn(__fmul_rn(6.283185307179586f, (float)u), 512.0f);
        const float cw = (float)cos((double)ang);
        const float w  = __fsub_rn(0.54f, __fmul_rn(0.46f, cw));
        v = __fmul_rn(v, w);
        evS[u] = v;
        ss += (double)v * (double)v;
    }
    red[tid] = ss; __syncthreads();
    for (int s = 128; s > 0; s >>= 1) { if (tid < s) red[tid] += red[tid+s]; __syncthreads(); }
    if (tid == 0) {
        const float nf = (float)sqrt(red[0]);
        scl[0] = __fadd_rn(nf, 1e-8f);
        float a = __fmul_rn(x[0], to_amp_w[0]);
        for (int l = 1; l < LDIM; ++l) a = __fadd_rn(a, __fmul_rn(x[l], to_amp_w[l]));
        scl[1] = __fadd_rn(a, to_amp_b[0]);
    }
    __syncthreads();
    const float den = scl[0], amp = scl[1];
    for (int u = tid; u < ASIZE; u += 256)
        zf[e*ASIZE + u] = __fmul_rn(__fdiv_rn(evS[u], den), amp);
}

// ---------------------------------------------------------------------------
// K3 (hot): forward, in-place radix-8^3 FFT-512 per wave. Grid: 385 b x 4
// event quarters; each wave owns 8 events + a private padded LDS buffer
// (pad f(j) = j + (j>>3), size 576). Stage0 fused with z*T modulate (register
// inputs); stage2 outputs stay in registers. Lane accumulates 8 bins in f32:
//   k1 = b + 768*(lane+64j)                 from bin a       (j = 0..3)
//   k2 = (768-b) + 768*(255-(lane+64j))     from conj(bin a+256)
// Cross-wave f32 reduction in LDS, contiguous f32 stores into quarter-partial
// Hq (flat: quarter*196609 + cls*256 + a; special k=196608 cell at +196608).
// ---------------------------------------------------------------------------
__global__ __launch_bounds__(256, 4) void forward_reg8(
    const float* __restrict__ zf, const float* __restrict__ sF,
    float* __restrict__ Hqf)
{
    __shared__ float2 FB[4*576];        // 18432 B wave-private padded buffers
    __shared__ float2 T[512];           // 4096 B
    __shared__ float2 W[448];           // 3584 B  (m*p*st <= 441)
    __shared__ float  sSh[32];
    const int b       = blockIdx.x >> 2;     // 0..384
    const int quarter = blockIdx.x & 3;
    const int tid  = threadIdx.x;
    const int wave = tid >> 6, lane = tid & 63;
    float2* F = FB + wave*576;
    const int e0 = quarter*32;

    for (int j = tid; j < 512; j += 256) {
        double s1, c1;
        sincos(-TWO_PI*(double)(b*j)/(double)NFFT, &s1, &c1);
        T[j] = make_float2((float)c1, (float)s1);
        if (j < 448) {
            sincos(-TWO_PI*(double)j/512.0, &s1, &c1);
            W[j] = make_float2((float)c1, (float)s1);
        }
    }
    if (tid < 32) sSh[tid] = sF[e0 + tid];
    __syncthreads();

    // f32 phase coefficient chains (bit-identical to np)
    float c2a[4], c2b[4];
    #pragma unroll
    for (int j = 0; j < 4; ++j) {
        const int a  = lane + 64*j;
        const int k1 = b + 768*a;
        const int k2 = (768 - b) + 768*(255 - a);
        c2a[j] = __fdiv_rn(__fmul_rn((float)(2*k1), 3.14159274101257324f), 196609.0f);
        c2b[j] = __fdiv_rn(__fmul_rn((float)(2*k2), 3.14159274101257324f), 196609.0f);
    }

    float a1R[4]={0,0,0,0}, a1I[4]={0,0,0,0};
    float a2R[4]={0,0,0,0}, a2I[4]={0,0,0,0};
    const int ph = lane + (lane >> 3);        // padded read base

    for (int it = 0; it < 8; ++it) {
        const int e = e0 + wave*8 + it;
        const float* zp = zf + e*ASIZE;
        // ---- stage 0 (st=1, p=lane): inputs z*T in registers
        {
            float2 i0,i1,i2,i3,i4,i5,i6,i7;
            {
                float z; float2 tt;
                z = zp[lane      ]; tt = T[lane      ]; i0 = make_float2(z*tt.x, z*tt.y);
                z = zp[lane +  64]; tt = T[lane +  64]; i1 = make_float2(z*tt.x, z*tt.y);
                z = zp[lane + 128]; tt = T[lane + 128]; i2 = make_float2(z*tt.x, z*tt.y);
                z = zp[lane + 192]; tt = T[lane + 192]; i3 = make_float2(z*tt.x, z*tt.y);
                z = zp[lane + 256]; tt = T[lane + 256]; i4 = make_float2(z*tt.x, z*tt.y);
                z = zp[lane + 320]; tt = T[lane + 320]; i5 = make_float2(z*tt.x, z*tt.y);
                z = zp[lane + 384]; tt = T[lane + 384]; i6 = make_float2(z*tt.x, z*tt.y);
                z = zp[lane + 448]; tt = T[lane + 448]; i7 = make_float2(z*tt.x, z*tt.y);
            }
            float2 x0,x1,x2,x3,x4,x5,x6,x7;
            DFT8F(i0,i1,i2,i3,i4,i5,i6,i7, x0,x1,x2,x3,x4,x5,x6,x7);
            const int ob = 9*lane;                 // phys(8p+m) = 9p+m
            const float2 wb = W[lane];
            float2 wm = wb;
            F[ob]   = x0;
            F[ob+1] = cmulf(x1, wm); wm = cmulf(wm, wb);
            F[ob+2] = cmulf(x2, wm); wm = cmulf(wm, wb);
            F[ob+3] = cmulf(x3, wm); wm = cmulf(wm, wb);
            F[ob+4] = cmulf(x4, wm); wm = cmulf(wm, wb);
            F[ob+5] = cmulf(x5, wm); wm = cmulf(wm, wb);
            F[ob+6] = cmulf(x6, wm); wm = cmulf(wm, wb);
            F[ob+7] = cmulf(x7, wm);
        }
        // ---- stage 1 (st=8): in-place (whole-wave reads precede writes)
        {
            const float2 i0 = F[ph      ], i1 = F[ph +  72], i2 = F[ph + 144],
                         i3 = F[ph + 216], i4 = F[ph + 288], i5 = F[ph + 360],
                         i6 = F[ph + 432], i7 = F[ph + 504];
            float2 x0,x1,x2,x3,x4,x5,x6,x7;
            DFT8F(i0,i1,i2,i3,i4,i5,i6,i7, x0,x1,x2,x3,x4,x5,x6,x7);
            const int q = lane & 7, p = lane >> 3;
            const int ob = q + 72*p;               // phys(q+64p+8m) = q+72p+9m
            const float2 wb = W[8*p];
            float2 wm = wb;
            F[ob]    = x0;
            F[ob+ 9] = cmulf(x1, wm); wm = cmulf(wm, wb);
            F[ob+18] = cmulf(x2, wm); wm = cmulf(wm, wb);
            F[ob+27] = cmulf(x3, wm); wm = cmulf(wm, wb);
            F[ob+36] = cmulf(x4, wm); wm = cmulf(wm, wb);
            F[ob+45] = cmulf(x5, wm); wm = cmulf(wm, wb);
            F[ob+54] = cmulf(x6, wm); wm = cmulf(wm, wb);
            F[ob+63] = cmulf(x7, wm);
        }
        // ---- stage 2 (st=64, p=0): outputs in registers, Y[m] = bin(lane+64m)
        float2 Y[8];
        {
            const float2 i0 = F[ph      ], i1 = F[ph +  72], i2 = F[ph + 144],
                         i3 = F[ph + 216], i4 = F[ph + 288], i5 = F[ph + 360],
                         i6 = F[ph + 432], i7 = F[ph + 504];
            DFT8F(i0,i1,i2,i3,i4,i5,i6,i7, Y[0],Y[1],Y[2],Y[3],Y[4],Y[5],Y[6],Y[7]);
        }
        // ---- accumulate (no divergence; unused k2 partials masked at store)
        const float se = sSh[wave*8 + it];
        #pragma unroll
        for (int j = 0; j < 4; ++j) {
            float ps, pc;
            const float2 S0 = Y[j];
            phase_sc(__fmul_rn(c2a[j], se), &ps, &pc);
            a1R[j] = fmaf(S0.x, pc, fmaf(-S0.y, ps, a1R[j]));
            a1I[j] = fmaf(S0.x, ps, fmaf( S0.y, pc, a1I[j]));
            const float2 S1 = Y[j+4];   // conj(S1) * e^{i theta}
            phase_sc(__fmul_rn(c2b[j], se), &ps, &pc);
            a2R[j] = fmaf(S1.x, pc, fmaf( S1.y, ps, a2R[j]));
            a2I[j] = fmaf(S1.x, ps, fmaf(-S1.y, pc, a2I[j]));
        }
    }

    // ---- cross-wave reduction (2 rounds in the FFT region) + stores
    float* redF = (float*)FB;
    #pragma unroll
    for (int round = 0; round < 2; ++round) {
        __syncthreads();
        const int j0 = 2*round;
        float* my = redF + (wave*64 + lane)*8;
        my[0]=a1R[j0];   my[1]=a1I[j0];   my[2]=a2R[j0];   my[3]=a2I[j0];
        my[4]=a1R[j0+1]; my[5]=a1I[j0+1]; my[6]=a2R[j0+1]; my[7]=a2I[j0+1];
        __syncthreads();
        const int s = tid >> 2, c = tid & 3;
        #pragma unroll
        for (int jr = 0; jr < 2; ++jr) {
            float v = 0.f;
            #pragma unroll
            for (int w = 0; w < 4; ++w) v += redF[(w*64 + s)*8 + jr*4 + c];
            const int as = s + 64*(j0 + jr);
            if (c < 2) {
                Hqf[2*(quarter*196609 + b*256 + as) + c] = v;
            } else if (b != 384) {
                if (b != 0)
                    Hqf[2*(quarter*196609 + (768-b)*256 + (255-as)) + (c-2)] = v;
                else if (as == 0)
                    Hqf[2*(quarter*196609 + 196608) + (c-2)] = v;
            }
        }
    }
}

// ---------------------------------------------------------------------------
// inverse radix-4 Stockham stage over 256 points, 64 threads, table twiddles
// (w = e^{+2pi i p*st/256} = Tw256[p*st]; verified math from R6/R7).
// ---------------------------------------------------------------------------
__device__ __forceinline__ void ifft256_stage(
    const double2* __restrict__ src, double2* __restrict__ dst, int t, int s4,
    const double2* __restrict__ Tw256)
{
    const int lg = 2*s4, st = 1 << lg;
    const int q = t & (st-1), p = t >> lg;
    const double2 A0 = src[t], A1 = src[t+64], A2 = src[t+128], A3 = src[t+192];
    const double Pr = A0.x + A2.x, Pi_ = A0.y + A2.y;
    const double Qr = A0.x - A2.x, Qi  = A0.y - A2.y;
    const double Rr = A1.x + A3.x, Ri  = A1.y + A3.y;
    const double Sr = A1.x - A3.x, Si  = A1.y - A3.y;
    const int tw = p*st;
    const double2 w1 = Tw256[tw];
    const double2 w2 = Tw256[(2*tw) & 255];
    const double2 w3 = Tw256[(3*tw) & 255];
    const int o = q + 4*st*p;
    dst[o] = make_double2(Pr + Rr, Pi_ + Ri);
    const double u1r = Qr - Si, u1i = Qi + Sr;
    dst[o + st]   = make_double2(u1r*w1.x - u1i*w1.y, u1r*w1.y + u1i*w1.x);
    const double u2r = Pr - Rr, u2i = Pi_ - Ri;
    dst[o + 2*st] = make_double2(u2r*w2.x - u2i*w2.y, u2r*w2.y + u2i*w2.x);
    const double u3r = Qr + Si, u3i = Qi - Sr;
    dst[o + 3*st] = make_double2(u3r*w3.x - u3i*w3.y, u3r*w3.y + u3i*w3.x);
}

// ---------------------------------------------------------------------------
// K4: inverse four-step, stage A. Job (l, j1), one wave each, 4 jobs/block:
// sum 4 quarter-partials of H at k = 3j1+l+768j2 (and Hermitian partner),
// pack G inline (table twiddle S*Tw512), FFT-256 over j2, four-step twiddle
// Tw256[hi]*Tw64k[lo] (j1*m1 = 256*hi+lo), store f32 Yg.
// ---------------------------------------------------------------------------
__global__ __launch_bounds__(256) void inv_a(
    const float* __restrict__ Hqf, const double2* __restrict__ Tw256,
    const double2* __restrict__ Tw512, const double2* __restrict__ Tw64k,
    float2* __restrict__ Yg)
{
    __shared__ double2 buf[4*512];
    const int tid = threadIdx.x;
    const int jj = tid >> 6, t = tid & 63;
    const int job = blockIdx.x*4 + jj;          // 0..767
    const int l = job >> 8, j1 = job & 255;
    const int k0 = 3*j1 + l;
    double2* A = buf + jj*512;
    double2* B = A + 256;
    const float2* Hq2 = (const float2*)Hqf;

    double Ss, Sc; sincos(TWO_PI*(double)k0/(double)NFFT, &Ss, &Sc);

    #pragma unroll
    for (int r = 0; r < 4; ++r) {
        const int j2 = t + 64*r;
        const int idxK = k0*256 + j2;
        int idxM;
        if (k0 > 0) idxM = (768 - k0)*256 + (255 - j2);
        else        idxM = (j2 == 0) ? 196608 : (256 - j2);
        double hkR=0, hkI=0, hmR=0, hmI=0;
        #pragma unroll
        for (int q = 0; q < 4; ++q) {
            const float2 vk = Hq2[q*196609 + idxK];
            const float2 vm = Hq2[q*196609 + idxM];
            hkR += (double)vk.x; hkI += (double)vk.y;
            hmR += (double)vm.x; hmI += (double)vm.y;
        }
        if (k0 == 0 && j2 == 0) { hkI = 0.0; hmI = 0.0; }  // irfft Im-drop
        const double Pr = hkR + hmR, Pi_ = hkI - hmI;
        const double Qr = hkR - hmR, Qi = hkI + hmI;
        const double2 t5 = Tw512[j2];                  // e^{2pi i j2/512}
        const double Wc = Sc*t5.x - Ss*t5.y;           // e^{2pi i k/NFFT}
        const double Wsn = Sc*t5.y + Ss*t5.x;
        const double WQr = Wc*Qr - Wsn*Qi;
        const double WQi = Wc*Qi + Wsn*Qr;
        A[j2] = make_double2(0.5*(Pr - WQi), 0.5*(Pi_ + WQr));
    }

    ifft256_stage(A, B, t, 0, Tw256);
    ifft256_stage(B, A, t, 1, Tw256);
    ifft256_stage(A, B, t, 2, Tw256);
    ifft256_stage(B, A, t, 3, Tw256);

    #pragma unroll
    for (int r = 0; r < 4; ++r) {
        const int m1 = t + 64*r;
        const double2 v = A[m1];
        const int vv = j1*m1;
        const double2 wa = Tw256[vv >> 8];
        const double2 wb = Tw64k[vv & 255];
        const double twc = wa.x*wb.x - wa.y*wb.y;
        const double tws = wa.x*wb.y + wa.y*wb.x;
        Yg[job*256 + m1] = make_float2((float)(v.x*twc - v.y*tws),
                                       (float)(v.x*tws + v.y*twc));
    }
}

// ---------------------------------------------------------------------------
// K5: inverse four-step, stage B + radix-3 combine + 1/M + f32 output.
// Block per m1; waves 0..2 handle l = 0..2; combine by all 256 threads.
// ---------------------------------------------------------------------------
__global__ __launch_bounds__(256) void inv_b(
    const float2* __restrict__ Yg, const double2* __restrict__ Tw256,
    const double2* __restrict__ Tw768, float* __restrict__ out)
{
    __shared__ double2 buf[3*512];
    const int m1 = blockIdx.x;
    const int tid = threadIdx.x;
    const int l = tid >> 6, t = tid & 63;
    if (l < 3) {
        double2* A = buf + l*512;
        double2* B = A + 256;
        #pragma unroll
        for (int r = 0; r < 4; ++r) {
            const int j1 = t + 64*r;
            const float2 g = Yg[(l*256 + j1)*256 + m1];
            A[j1] = make_double2((double)g.x, (double)g.y);
        }
        ifft256_stage(A, B, t, 0, Tw256);
        ifft256_stage(B, A, t, 1, Tw256);
        ifft256_stage(A, B, t, 2, Tw256);
        ifft256_stage(B, A, t, 3, Tw256);
    }
    __syncthreads();

    const int m2 = tid;
    const double2 F0 = buf[0*512 + m2];
    const double2 F1 = buf[1*512 + m2];
    const double2 F2 = buf[2*512 + m2];
    double sm, cm; sincos(TWO_PI*(double)m1/(double)MHALF, &sm, &cm);
    const double2 t7 = Tw768[m2];                    // e^{2pi i m2/768}
    const double w1c = cm*t7.x - sm*t7.y, w1s = cm*t7.y + sm*t7.x;
    const double w2c = w1c*w1c - w1s*w1s, w2s = 2.0*w1c*w1s;
    const double gr = F0.x + (w1c*F1.x - w1s*F1.y) + (w2c*F2.x - w2s*F2.y);
    const double gi = F0.y + (w1c*F1.y + w1s*F1.x) + (w2c*F2.y + w2s*F2.x);
    const int m = m1 + 256*m2;
    const double inv = 1.0/(double)MHALF;
    out[2*m]     = (float)(gr*inv);
    out[2*m + 1] = (float)(gi*inv);
}

// ---------------------------------------------------------------------------
extern "C" void kernel_launch(void* const* d_in, const int* in_sizes, int n_in,
                              void* d_out, int out_size, void* d_ws, size_t ws_size,
                              hipStream_t stream) {
    const float* base       = (const float*)d_in[0];
    const float* to_off_w   = (const float*)d_in[1];
    const float* split_w    = (const float*)d_in[2];
    const float* split_b    = (const float*)d_in[3];
    const float* atoms      = (const float*)d_in[4];
    const float* to_atoms_w = (const float*)d_in[5];
    const float* to_atoms_b = (const float*)d_in[6];
    const float* to_amp_w   = (const float*)d_in[7];
    const float* to_amp_b   = (const float*)d_in[8];
    float* out = (float*)d_out;

    // workspace layout: 8,151,584 B total (< 9,715,728 proven-safe in R4)
    char* ws = (char*)d_ws;
    double2* Tw256 = (double2*)(ws + 0);        //  4096
    double2* Tw512 = (double2*)(ws + 4096);     //  4096
    double2* Tw768 = (double2*)(ws + 8192);     //  4096
    double2* Tw64k = (double2*)(ws + 12288);    //  4096 -> 16384
    float*   sF    = (float*)(ws + 16384);      //   512
    float*   xF    = (float*)(ws + 16896);      //  8192 -> 25088
    float*   zf    = (float*)(ws + 25088);      // 262144 -> 287232
    float*   Hqf   = (float*)(ws + 287232);     // 4*196609*8 = 6291488 -> 6578720
    float2*  Yg    = (float2*)(ws + 6578720);   // 768*256*8 = 1572864 -> 8151584

    twiddles<<<1, 256, 0, stream>>>(Tw256, Tw512, Tw768, Tw64k);
    tree_f32<<<1, 256, 0, stream>>>(base, to_off_w, split_w, split_b, xF, sF);
    events_f32<<<NEV, 256, 0, stream>>>(atoms, to_atoms_w, to_atoms_b,
                                        to_amp_w, to_amp_b, xF, zf);
    forward_reg8<<<385*4, 256, 0, stream>>>(zf, sF, Hqf);
    inv_a<<<192, 256, 0, stream>>>(Hqf, Tw256, Tw512, Tw64k, Yg);
    inv_b<<<256, 256, 0, stream>>>(Yg, Tw256, Tw768, out);
}

// Round 9
// 138.348 us; speedup vs baseline: 26.0319x; 1.0583x over previous
//
#include <hip/hip_runtime.h>
#include <hip/hip_bf16.h>
#include <math.h>

// Problem constants
constexpr int NSAMP  = 131072;
constexpr int NEV    = 128;
constexpr int ASIZE  = 512;
constexpr int LDIM   = 16;
constexpr int NLAYER = 7;
constexpr int NFFT   = 393216;     // padded FFT length (3*NSAMP)
constexpr int MHALF  = 196608;     // NFFT/2
constexpr double TWO_PI = 6.283185307179586;

// Pipeline: f32-faithful front-end (bit-exact bt -> s), f32-quantized phases
// theta = f32(f32(2k*pi_f32)/196609f * s) [the ghost field], f32 spectra
// partials, inverse real FFT = radix-3 split x (256x256 four-step, ALL f32 —
// R8 empirically showed f32 Yg leaves absmax unchanged; error model ~2e-9).
// Forward: k = b + 768a, S_e(b+768a) = FFT512_a{ z_e[u]*T_b[u] }; Hermitian
// trick -> b in [0,384]. FFT-512 = 3 in-place radix-8 stages, wave-private,
// register-staged (same-wave DS ordering validated R7/R8). T rows from L2,
// twiddle bases in registers -> LDS 18.6 KB -> 3 blocks/CU (64 KB pool).

__device__ __forceinline__ float2 cmulf(float2 a, float2 b) {
    return make_float2(a.x*b.x - a.y*b.y, a.x*b.y + a.y*b.x);
}
__device__ __forceinline__ float2 CADD(float2 a, float2 b){ return make_float2(a.x+b.x, a.y+b.y); }
__device__ __forceinline__ float2 CSUB(float2 a, float2 b){ return make_float2(a.x-b.x, a.y-b.y); }

// sin/cos of the EXACT value of a float32 phase (magnitude up to ~8e5):
// exact mod-2pi reduction in double via two fmas, then fast f32 sincos.
__device__ __forceinline__ void phase_sc(float th32, float* ps, float* pc) {
    const double th = (double)th32;
    const double n  = rint(th * 0.15915494309189535);
    double r = fma(-n, 6.283185307179586, th);
    r = fma(-n, 2.4492935982947064e-16, r);
    __sincosf((float)r, ps, pc);
}

// forward DFT-8 on registers (verified, R8)
#define RT2 0.70710678118654752f
#define DFT8F(A0,A1,A2,A3,A4,A5,A6,A7, X0,X1,X2,X3,X4,X5,X6,X7) { \
  float2 b0=CADD(A0,A4), b1=CADD(A1,A5), b2=CADD(A2,A6), b3=CADD(A3,A7); \
  float2 c0=CSUB(A0,A4); \
  float2 d1=CSUB(A1,A5), d2=CSUB(A2,A6), d3=CSUB(A3,A7); \
  float2 c1=make_float2((d1.x+d1.y)*RT2, (d1.y-d1.x)*RT2); \
  float2 c2=make_float2(d2.y, -d2.x); \
  float2 c3=make_float2((d3.y-d3.x)*RT2, -(d3.x+d3.y)*RT2); \
  float2 t0=CADD(b0,b2), t1=CSUB(b0,b2), t2=CADD(b1,b3), t3=CSUB(b1,b3); \
  X0=CADD(t0,t2); X4=CSUB(t0,t2); \
  X2=make_float2(t1.x+t3.y, t1.y-t3.x); X6=make_float2(t1.x-t3.y, t1.y+t3.x); \
  t0=CADD(c0,c2); t1=CSUB(c0,c2); t2=CADD(c1,c3); t3=CSUB(c1,c3); \
  X1=CADD(t0,t2); X5=CSUB(t0,t2); \
  X3=make_float2(t1.x+t3.y, t1.y-t3.x); X7=make_float2(t1.x-t3.y, t1.y+t3.x); \
}

// ---------------------------------------------------------------------------
// K1: fused init. Block 0: latent tree (strict f32, bit-identical to R4-R8).
// Block 1: f32 inverse twiddle tables. Blocks 2..386: Ttab row b = blk-2,
// T_b[j] = (float)e^{-2pi i b j / NFFT} (fp64 sincos -> bit-identical to R8).
// ---------------------------------------------------------------------------
__global__ __launch_bounds__(256) void init_all(
    const float* __restrict__ base, const float* __restrict__ to_off_w,
    const float* __restrict__ split_w, const float* __restrict__ split_b,
    float* __restrict__ xF, float* __restrict__ sF,
    float2* __restrict__ Twf, float2* __restrict__ Ttab)
{
    const int blk = blockIdx.x;
    const int tid = threadIdx.x;
    if (blk == 0) {
        __shared__ float xA[NEV*LDIM], xB[NEV*LDIM], bA[NEV], bB[NEV];
        if (tid < LDIM) xA[tid] = base[tid];
        if (tid == 0) bA[0] = 0.0f;
        __syncthreads();
        float* xi = xA; float* xo = xB; float* bi = bA; float* bo = bB;
        for (int i = 0; i < NLAYER; ++i) {
            const int ein = 1 << i;
            const float scale = 1.0f / (float)(1 << i);
            for (int idx = tid; idx < ein*32; idx += 256) {
                const int ep = idx >> 5, o2 = idx & 31;
                const float* wr = split_w + (i*32 + o2)*LDIM;
                const float* xr = xi + ep*LDIM;
                float s = __fmul_rn(xr[0], wr[0]);
                for (int l = 1; l < LDIM; ++l)
                    s = __fadd_rn(s, __fmul_rn(xr[l], wr[l]));
                s = __fadd_rn(s, split_b[i*32 + o2]);
                xo[(ep*2 + (o2>>4))*LDIM + (o2&15)] = s;
            }
            for (int idx = tid; idx < ein*2; idx += 256) {
                const int ep = idx >> 1, o = idx & 1;
                const float* wr = to_off_w + (i*2 + o)*LDIM;
                const float* xr = xi + ep*LDIM;
                float v = __fmul_rn(xr[0], wr[0]);
                for (int l = 1; l < LDIM; ++l)
                    v = __fadd_rn(v, __fmul_rn(xr[l], wr[l]));
                const float ef = (float)exp(-(double)v);
                const float sg = __fdiv_rn(1.0f, __fadd_rn(1.0f, ef));
                bo[ep*2 + o] = __fadd_rn(bi[ep], __fmul_rn(sg, scale));
            }
            __syncthreads();
            float* t;
            t = xi; xi = xo; xo = t;
            t = bi; bi = bo; bo = t;
        }
        for (int idx = tid; idx < NEV*LDIM; idx += 256) xF[idx] = xi[idx];
        for (int e = tid; e < NEV; e += 256)
            sF[e] = __fmul_rn(__fmul_rn(bi[e], 131072.0f), 0.5f);
        return;
    }
    if (blk == 1) {
        double s, c;
        sincos(TWO_PI*(double)tid/256.0,   &s, &c); Twf[tid]       = make_float2((float)c,(float)s);
        sincos(TWO_PI*(double)tid/512.0,   &s, &c); Twf[256 + tid] = make_float2((float)c,(float)s);
        sincos(TWO_PI*(double)tid/768.0,   &s, &c); Twf[512 + tid] = make_float2((float)c,(float)s);
        sincos(TWO_PI*(double)tid/65536.0, &s, &c); Twf[768 + tid] = make_float2((float)c,(float)s);
        return;
    }
    const int b = blk - 2;                       // 0..384
    for (int j = tid; j < 512; j += 256) {
        double s, c;
        sincos(-TWO_PI*(double)(b*j)/(double)NFFT, &s, &c);
        Ttab[b*512 + j] = make_float2((float)c, (float)s);
    }
}

// ---------------------------------------------------------------------------
// K2: per-event signal, strict f32 chain (mix -> window -> norm -> amp).
// ---------------------------------------------------------------------------
__global__ __launch_bounds__(256) void events_f32(
    const float* __restrict__ atoms, const float* __restrict__ to_atoms_w,
    const float* __restrict__ to_atoms_b, const float* __restrict__ to_amp_w,
    const float* __restrict__ to_amp_b, const float* __restrict__ xF,
    float* __restrict__ zf)
{
    const int e = blockIdx.x;
    const int tid = threadIdx.x;
    __shared__ float mixS[32];
    __shared__ float evS[ASIZE];
    __shared__ double red[256];
    __shared__ float scl[2];
    const float* x = xF + e*LDIM;
    if (tid < 32) {
        const float* wr = to_atoms_w + tid*LDIM;
        float m = __fmul_rn(x[0], wr[0]);
        for (int l = 1; l < LDIM; ++l) m = __fadd_rn(m, __fmul_rn(x[l], wr[l]));
        mixS[tid] = __fadd_rn(m, to_atoms_b[tid]);
    }
    __syncthreads();
    double ss = 0.0;
    for (int u = tid; u < ASIZE; u += 256) {
        float v = __fmul_rn(mixS[0], atoms[u]);
        for (int a = 1; a < 32; ++a)
            v = __fadd_rn(v, __fmul_rn(mixS[a], atoms[a*ASIZE + u]));
        const float ang = __fdiv_rn(__fmul_rn(6.283185307179586f, (float)u), 512.0f);
        const float cw = (float)cos((double)ang);
        const float w  = __fsub_rn(0.54f, __fmul_rn(0.46f, cw));
        v = __fmul_rn(v, w);
        evS[u] = v;
        ss += (double)v * (double)v;
    }
    red[tid] = ss; __syncthreads();
    for (int s = 128; s > 0; s >>= 1) { if (tid < s) red[tid] += red[tid+s]; __syncthreads(); }
    if (tid == 0) {
        const float nf = (float)sqrt(red[0]);
        scl[0] = __fadd_rn(nf, 1e-8f);
        float a = __fmul_rn(x[0], to_amp_w[0]);
        for (int l = 1; l < LDIM; ++l) a = __fadd_rn(a, __fmul_rn(x[l], to_amp_w[l]));
        scl[1] = __fadd_rn(a, to_amp_b[0]);
    }
    __syncthreads();
    const float den = scl[0], amp = scl[1];
    for (int u = tid; u < ASIZE; u += 256)
        zf[e*ASIZE + u] = __fmul_rn(__fdiv_rn(evS[u], den), amp);
}

// ---------------------------------------------------------------------------
// K3 (hot): forward, in-place radix-8^3 FFT-512 per wave (R8 structure).
// LDS = FFT buffers + sSh only (18.6 KB -> 3 blocks/CU in the 64 KB pool).
// T row read from global (L2-hot); stage twiddle bases in registers.
// ---------------------------------------------------------------------------
__global__ __launch_bounds__(256, 3) void forward_v2(
    const float* __restrict__ zf, const float* __restrict__ sF,
    const float2* __restrict__ Ttab, float* __restrict__ Hqf)
{
    __shared__ float2 FB[4*576];        // 18432 B wave-private padded buffers
    __shared__ float  sSh[32];
    const int b       = blockIdx.x >> 2;     // 0..384
    const int quarter = blockIdx.x & 3;
    const int tid  = threadIdx.x;
    const int wave = tid >> 6, lane = tid & 63;
    float2* F = FB + wave*576;
    const int e0 = quarter*32;
    const float2* Tg = Ttab + b*512;

    if (tid < 32) sSh[tid] = sF[e0 + tid];
    __syncthreads();

    // register twiddle bases (FFT-internal; slop-tolerant)
    float2 w0b, w1b;
    __sincosf(-6.283185307179586f/512.0f * (float)lane,        &w0b.y, &w0b.x);
    __sincosf(-6.283185307179586f/64.0f  * (float)(lane >> 3), &w1b.y, &w1b.x);

    // f32 phase coefficient chains (bit-identical to np)
    float c2a[4], c2b[4];
    #pragma unroll
    for (int j = 0; j < 4; ++j) {
        const int a  = lane + 64*j;
        const int k1 = b + 768*a;
        const int k2 = (768 - b) + 768*(255 - a);
        c2a[j] = __fdiv_rn(__fmul_rn((float)(2*k1), 3.14159274101257324f), 196609.0f);
        c2b[j] = __fdiv_rn(__fmul_rn((float)(2*k2), 3.14159274101257324f), 196609.0f);
    }

    float a1R[4]={0,0,0,0}, a1I[4]={0,0,0,0};
    float a2R[4]={0,0,0,0}, a2I[4]={0,0,0,0};
    const int ph = lane + (lane >> 3);        // padded read base

    for (int it = 0; it < 8; ++it) {
        const int e = e0 + wave*8 + it;
        const float* zp = zf + e*ASIZE;
        // ---- stage 0 (st=1, p=lane): inputs z*T in registers
        {
            float2 i0,i1,i2,i3,i4,i5,i6,i7;
            {
                float z; float2 tt;
                z = zp[lane      ]; tt = Tg[lane      ]; i0 = make_float2(z*tt.x, z*tt.y);
                z = zp[lane +  64]; tt = Tg[lane +  64]; i1 = make_float2(z*tt.x, z*tt.y);
                z = zp[lane + 128]; tt = Tg[lane + 128]; i2 = make_float2(z*tt.x, z*tt.y);
                z = zp[lane + 192]; tt = Tg[lane + 192]; i3 = make_float2(z*tt.x, z*tt.y);
                z = zp[lane + 256]; tt = Tg[lane + 256]; i4 = make_float2(z*tt.x, z*tt.y);
                z = zp[lane + 320]; tt = Tg[lane + 320]; i5 = make_float2(z*tt.x, z*tt.y);
                z = zp[lane + 384]; tt = Tg[lane + 384]; i6 = make_float2(z*tt.x, z*tt.y);
                z = zp[lane + 448]; tt = Tg[lane + 448]; i7 = make_float2(z*tt.x, z*tt.y);
            }
            float2 x0,x1,x2,x3,x4,x5,x6,x7;
            DFT8F(i0,i1,i2,i3,i4,i5,i6,i7, x0,x1,x2,x3,x4,x5,x6,x7);
            const int ob = 9*lane;                 // phys(8p+m) = 9p+m
            float2 wm = w0b;
            F[ob]   = x0;
            F[ob+1] = cmulf(x1, wm); wm = cmulf(wm, w0b);
            F[ob+2] = cmulf(x2, wm); wm = cmulf(wm, w0b);
            F[ob+3] = cmulf(x3, wm); wm = cmulf(wm, w0b);
            F[ob+4] = cmulf(x4, wm); wm = cmulf(wm, w0b);
            F[ob+5] = cmulf(x5, wm); wm = cmulf(wm, w0b);
            F[ob+6] = cmulf(x6, wm); wm = cmulf(wm, w0b);
            F[ob+7] = cmulf(x7, wm);
        }
        // ---- stage 1 (st=8): in-place (whole-wave reads precede writes)
        {
            const float2 i0 = F[ph      ], i1 = F[ph +  72], i2 = F[ph + 144],
                         i3 = F[ph + 216], i4 = F[ph + 288], i5 = F[ph + 360],
                         i6 = F[ph + 432], i7 = F[ph + 504];
            float2 x0,x1,x2,x3,x4,x5,x6,x7;
            DFT8F(i0,i1,i2,i3,i4,i5,i6,i7, x0,x1,x2,x3,x4,x5,x6,x7);
            const int q = lane & 7, p = lane >> 3;
            const int ob = q + 72*p;               // phys(q+64p+8m) = q+72p+9m
            float2 wm = w1b;
            F[ob]    = x0;
            F[ob+ 9] = cmulf(x1, wm); wm = cmulf(wm, w1b);
            F[ob+18] = cmulf(x2, wm); wm = cmulf(wm, w1b);
            F[ob+27] = cmulf(x3, wm); wm = cmulf(wm, w1b);
            F[ob+36] = cmulf(x4, wm); wm = cmulf(wm, w1b);
            F[ob+45] = cmulf(x5, wm); wm = cmulf(wm, w1b);
            F[ob+54] = cmulf(x6, wm); wm = cmulf(wm, w1b);
            F[ob+63] = cmulf(x7, wm);
        }
        // ---- stage 2 (st=64, p=0): outputs in registers, Y[m] = bin(lane+64m)
        float2 Y[8];
        {
            const float2 i0 = F[ph      ], i1 = F[ph +  72], i2 = F[ph + 144],
                         i3 = F[ph + 216], i4 = F[ph + 288], i5 = F[ph + 360],
                         i6 = F[ph + 432], i7 = F[ph + 504];
            DFT8F(i0,i1,i2,i3,i4,i5,i6,i7, Y[0],Y[1],Y[2],Y[3],Y[4],Y[5],Y[6],Y[7]);
        }
        // ---- accumulate
        const float se = sSh[wave*8 + it];
        #pragma unroll
        for (int j = 0; j < 4; ++j) {
            float ps, pc;
            const float2 S0 = Y[j];
            phase_sc(__fmul_rn(c2a[j], se), &ps, &pc);
            a1R[j] = fmaf(S0.x, pc, fmaf(-S0.y, ps, a1R[j]));
            a1I[j] = fmaf(S0.x, ps, fmaf( S0.y, pc, a1I[j]));
            const float2 S1 = Y[j+4];   // conj(S1) * e^{i theta}
            phase_sc(__fmul_rn(c2b[j], se), &ps, &pc);
            a2R[j] = fmaf(S1.x, pc, fmaf( S1.y, ps, a2R[j]));
            a2I[j] = fmaf(S1.x, ps, fmaf(-S1.y, pc, a2I[j]));
        }
    }

    // ---- cross-wave reduction (2 rounds in the FFT region) + stores
    float* redF = (float*)FB;
    #pragma unroll
    for (int round = 0; round < 2; ++round) {
        __syncthreads();
        const int j0 = 2*round;
        float* my = redF + (wave*64 + lane)*8;
        my[0]=a1R[j0];   my[1]=a1I[j0];   my[2]=a2R[j0];   my[3]=a2I[j0];
        my[4]=a1R[j0+1]; my[5]=a1I[j0+1]; my[6]=a2R[j0+1]; my[7]=a2I[j0+1];
        __syncthreads();
        const int s = tid >> 2, c = tid & 3;
        #pragma unroll
        for (int jr = 0; jr < 2; ++jr) {
            float v = 0.f;
            #pragma unroll
            for (int w = 0; w < 4; ++w) v += redF[(w*64 + s)*8 + jr*4 + c];
            const int as = s + 64*(j0 + jr);
            if (c < 2) {
                Hqf[2*(quarter*196609 + b*256 + as) + c] = v;
            } else if (b != 384) {
                if (b != 0)
                    Hqf[2*(quarter*196609 + (768-b)*256 + (255-as)) + (c-2)] = v;
                else if (as == 0)
                    Hqf[2*(quarter*196609 + 196608) + (c-2)] = v;
            }
        }
    }
}

// ---------------------------------------------------------------------------
// inverse radix-4 Stockham stage over 256 points, 64 threads, f32, table
// twiddles (w = e^{+2pi i p*st/256} = Tw256f[p*st]; math verified R6-R8).
// ---------------------------------------------------------------------------
__device__ __forceinline__ void ifft256f_stage(
    const float2* __restrict__ src, float2* __restrict__ dst, int t, int s4,
    const float2* __restrict__ Tw256f)
{
    const int lg = 2*s4, st = 1 << lg;
    const int q = t & (st-1), p = t >> lg;
    const float2 A0 = src[t], A1 = src[t+64], A2 = src[t+128], A3 = src[t+192];
    const float Pr = A0.x + A2.x, Pi_ = A0.y + A2.y;
    const float Qr = A0.x - A2.x, Qi  = A0.y - A2.y;
    const float Rr = A1.x + A3.x, Ri  = A1.y + A3.y;
    const float Sr = A1.x - A3.x, Si  = A1.y - A3.y;
    const int tw = p*st;
    const float2 w1 = Tw256f[tw];
    const float2 w2 = Tw256f[(2*tw) & 255];
    const float2 w3 = Tw256f[(3*tw) & 255];
    const int o = q + 4*st*p;
    dst[o] = make_float2(Pr + Rr, Pi_ + Ri);
    const float u1r = Qr - Si, u1i = Qi + Sr;
    dst[o + st]   = make_float2(u1r*w1.x - u1i*w1.y, u1r*w1.y + u1i*w1.x);
    const float u2r = Pr - Rr, u2i = Pi_ - Ri;
    dst[o + 2*st] = make_float2(u2r*w2.x - u2i*w2.y, u2r*w2.y + u2i*w2.x);
    const float u3r = Qr + Si, u3i = Qi - Sr;
    dst[o + 3*st] = make_float2(u3r*w3.x - u3i*w3.y, u3r*w3.y + u3i*w3.x);
}

// ---------------------------------------------------------------------------
// K4: inverse four-step, stage A. ONE single-wave block per job (l, j1):
// sum 4 quarter-partials of H at k = 3j1+l+768j2 (+ Hermitian partner),
// pack G inline, f32 FFT-256 over j2, four-step twiddle, TRANSPOSED store
// Yg[m1*768 + job] (coalesced reads in stage B). No barriers (1 wave).
// ---------------------------------------------------------------------------
__global__ __launch_bounds__(64) void inv_a(
    const float* __restrict__ Hqf, const float2* __restrict__ Twf,
    float2* __restrict__ Yg)
{
    __shared__ float2 buf[512];
    const int t = threadIdx.x;
    const int job = blockIdx.x;                 // 0..767
    const int l = job >> 8, j1 = job & 255;
    const int k0 = 3*j1 + l;
    float2* A = buf; float2* B = buf + 256;
    const float2* Hq2 = (const float2*)Hqf;
    const float2* Tw256f = Twf;
    const float2* Tw512f = Twf + 256;
    const float2* Tw64kf = Twf + 768;

    double Ss, Sc; sincos(TWO_PI*(double)k0/(double)NFFT, &Ss, &Sc);
    const float Scf = (float)Sc, Ssf = (float)Ss;

    #pragma unroll
    for (int r = 0; r < 4; ++r) {
        const int j2 = t + 64*r;
        const int idxK = k0*256 + j2;
        int idxM;
        if (k0 > 0) idxM = (768 - k0)*256 + (255 - j2);
        else        idxM = (j2 == 0) ? 196608 : (256 - j2);
        float hkR=0.f, hkI=0.f, hmR=0.f, hmI=0.f;
        #pragma unroll
        for (int q = 0; q < 4; ++q) {
            const float2 vk = Hq2[q*196609 + idxK];
            const float2 vm = Hq2[q*196609 + idxM];
            hkR += vk.x; hkI += vk.y;
            hmR += vm.x; hmI += vm.y;
        }
        if (k0 == 0 && j2 == 0) { hkI = 0.f; hmI = 0.f; }  // irfft Im-drop
        const float Pr = hkR + hmR, Pi_ = hkI - hmI;
        const float Qr = hkR - hmR, Qi = hkI + hmI;
        const float2 t5 = Tw512f[j2];                  // e^{2pi i j2/512}
        const float Wc = Scf*t5.x - Ssf*t5.y;          // e^{2pi i k/NFFT}
        const float Wsn = Scf*t5.y + Ssf*t5.x;
        const float WQr = Wc*Qr - Wsn*Qi;
        const float WQi = Wc*Qi + Wsn*Qr;
        A[j2] = make_float2(0.5f*(Pr - WQi), 0.5f*(Pi_ + WQr));
    }

    ifft256f_stage(A, B, t, 0, Tw256f);
    ifft256f_stage(B, A, t, 1, Tw256f);
    ifft256f_stage(A, B, t, 2, Tw256f);
    ifft256f_stage(B, A, t, 3, Tw256f);

    #pragma unroll
    for (int r = 0; r < 4; ++r) {
        const int m1 = t + 64*r;
        const float2 v = A[m1];
        const int vv = j1*m1;
        const float2 wa = Tw256f[vv >> 8];
        const float2 wb = Tw64kf[vv & 255];
        const float twc = wa.x*wb.x - wa.y*wb.y;
        const float tws = wa.x*wb.y + wa.y*wb.x;
        Yg[m1*768 + job] = make_float2(v.x*twc - v.y*tws, v.x*tws + v.y*twc);
    }
}

// ---------------------------------------------------------------------------
// K5: inverse four-step, stage B + radix-3 combine + 1/M + f32 output.
// Block per m1, 192 threads = 3 single-wave FFT jobs (l = 0..2), then combine.
// ---------------------------------------------------------------------------
__global__ __launch_bounds__(192) void inv_b(
    const float2* __restrict__ Yg, const float2* __restrict__ Twf,
    float* __restrict__ out)
{
    __shared__ float2 buf[3*512];
    const int m1 = blockIdx.x;
    const int tid = threadIdx.x;
    const int l = tid >> 6, t = tid & 63;
    const float2* Tw256f = Twf;
    const float2* Tw768f = Twf + 512;
    {
        float2* A = buf + l*512;
        float2* B = A + 256;
        #pragma unroll
        for (int r = 0; r < 4; ++r) {
            const int j1 = t + 64*r;
            A[j1] = Yg[m1*768 + l*256 + j1];      // coalesced
        }
        ifft256f_stage(A, B, t, 0, Tw256f);
        ifft256f_stage(B, A, t, 1, Tw256f);
        ifft256f_stage(A, B, t, 2, Tw256f);
        ifft256f_stage(B, A, t, 3, Tw256f);
    }
    __syncthreads();

    double smd, cmd; sincos(TWO_PI*(double)m1/(double)MHALF, &smd, &cmd);
    const float cm = (float)cmd, sm = (float)smd;
    const float inv = 1.0f/(float)MHALF;
    for (int m2 = tid; m2 < 256; m2 += 192) {
        const float2 F0 = buf[m2];
        const float2 F1 = buf[512 + m2];
        const float2 F2 = buf[1024 + m2];
        const float2 t7 = Tw768f[m2];                 // e^{2pi i m2/768}
        const float w1c = cm*t7.x - sm*t7.y, w1s = cm*t7.y + sm*t7.x;
        const float w2c = w1c*w1c - w1s*w1s, w2s = 2.0f*w1c*w1s;
        const float gr = F0.x + (w1c*F1.x - w1s*F1.y) + (w2c*F2.x - w2s*F2.y);
        const float gi = F0.y + (w1c*F1.y + w1s*F1.x) + (w2c*F2.y + w2s*F2.x);
        const int m = m1 + 256*m2;
        out[2*m]     = gr*inv;
        out[2*m + 1] = gi*inv;
    }
}

// ---------------------------------------------------------------------------
extern "C" void kernel_launch(void* const* d_in, const int* in_sizes, int n_in,
                              void* d_out, int out_size, void* d_ws, size_t ws_size,
                              hipStream_t stream) {
    const float* base       = (const float*)d_in[0];
    const float* to_off_w   = (const float*)d_in[1];
    const float* split_w    = (const float*)d_in[2];
    const float* split_b    = (const float*)d_in[3];
    const float* atoms      = (const float*)d_in[4];
    const float* to_atoms_w = (const float*)d_in[5];
    const float* to_atoms_b = (const float*)d_in[6];
    const float* to_amp_w   = (const float*)d_in[7];
    const float* to_amp_b   = (const float*)d_in[8];
    float* out = (float*)d_out;

    // workspace layout: 8,147,488 B (< 9,715,728 proven-safe in R4).
    // Yg aliases Ttab: forward (last Ttab reader) completes before inv_a.
    char* ws = (char*)d_ws;
    float2* Twf  = (float2*)(ws + 0);          // 4*256*8 = 8192
    float*  sF   = (float*)(ws + 8192);        //   512
    float*  xF   = (float*)(ws + 8704);        //  8192 -> 16896
    float*  zf   = (float*)(ws + 16896);       // 262144 -> 279040
    float2* Ttab = (float2*)(ws + 279040);     // 385*512*8 = 1576960 -> 1856000
    float2* Yg   = (float2*)(ws + 279040);     // 768*256*8 = 1572864 (alias)
    float*  Hqf  = (float*)(ws + 1856000);     // 4*196609*8 = 6291488 -> 8147488

    init_all<<<387, 256, 0, stream>>>(base, to_off_w, split_w, split_b,
                                      xF, sF, Twf, Ttab);
    events_f32<<<NEV, 256, 0, stream>>>(atoms, to_atoms_w, to_atoms_b,
                                        to_amp_w, to_amp_b, xF, zf);
    forward_v2<<<385*4, 256, 0, stream>>>(zf, sF, Ttab, Hqf);
    inv_a<<<768, 64, 0, stream>>>(Hqf, Twf, Yg);
    inv_b<<<256, 192, 0, stream>>>(Yg, Twf, out);
}